// Round 5
// baseline (1358.185 us; speedup 1.0000x reference)
//
#include <hip/hip_runtime.h>
#include <math.h>

#define NN 50000
#define NE 800000
#define DIN 32
#define D 128
#define NL 3
#define NG 64
#define LN_EPS 1e-5f

typedef unsigned short u16;
typedef __bf16 bf16x8 __attribute__((ext_vector_type(8)));
typedef float f32x4 __attribute__((ext_vector_type(4)));

__device__ __forceinline__ float gelu_f(float x) {
    return 0.5f * x * (1.0f + erff(x * 0.70710678118654752f));
}

__device__ __forceinline__ u16 f2bf(float x) {
    unsigned int u = __float_as_uint(x);
    u += 0x7fffu + ((u >> 16) & 1u);
    return (u16)(u >> 16);
}

__device__ __forceinline__ void unpack8(uint4 p, float* f) {
    f[0] = __uint_as_float(p.x << 16); f[1] = __uint_as_float(p.x & 0xffff0000u);
    f[2] = __uint_as_float(p.y << 16); f[3] = __uint_as_float(p.y & 0xffff0000u);
    f[4] = __uint_as_float(p.z << 16); f[5] = __uint_as_float(p.z & 0xffff0000u);
    f[6] = __uint_as_float(p.w << 16); f[7] = __uint_as_float(p.w & 0xffff0000u);
}

// ---------------- counting sort of edges by dst ----------------
__global__ __launch_bounds__(256) void hist_kernel(
    const int* __restrict__ dst, int* __restrict__ hist)
{
    int e = blockIdx.x * 256 + threadIdx.x;
    atomicAdd(&hist[dst[e]], 1);
}

__global__ __launch_bounds__(1024) void scan_kernel(
    const int* __restrict__ hist, int* __restrict__ cursor)
{
    __shared__ int part[1024];
    const int t = threadIdx.x;
    const int CH = (NN + 1023) / 1024;
    int beg = t * CH, end = beg + CH;
    if (end > NN) end = NN;
    int s = 0;
    for (int i = beg; i < end; ++i) s += hist[i];
    part[t] = s;
    __syncthreads();
    for (int off = 1; off < 1024; off <<= 1) {
        int v = (t >= off) ? part[t - off] : 0;
        __syncthreads();
        part[t] += v;
        __syncthreads();
    }
    int run = (t > 0) ? part[t - 1] : 0;
    for (int i = beg; i < end; ++i) {
        cursor[i] = run;
        run += hist[i];
    }
}

__global__ __launch_bounds__(256) void scatter_kernel(
    const int* __restrict__ src, const int* __restrict__ dst,
    const float* __restrict__ ew, int* __restrict__ cursor,
    int* __restrict__ sSrc, int* __restrict__ sDst, float* __restrict__ sEw)
{
    int e = blockIdx.x * 256 + threadIdx.x;
    int d = dst[e];
    int pos = atomicAdd(&cursor[d], 1);
    sSrc[pos] = src[e];
    sDst[pos] = d;
    sEw[pos] = ew[e];
}

// ---------------- projections / weight prep ----------------
__global__ __launch_bounds__(256) void input_proj_kernel(
    const float* __restrict__ X, const float* __restrict__ W,
    const float* __restrict__ b, u16* __restrict__ hbf)
{
    __shared__ float sW[DIN * D];
    for (int i = threadIdx.x; i < DIN * D; i += 256) sW[i] = W[i];
    __syncthreads();
    int o = blockIdx.x * 256 + threadIdx.x;
    int n = o >> 7, d = o & 127;
    const float* x = X + n * DIN;
    float acc = b[d];
#pragma unroll
    for (int k = 0; k < DIN; ++k) acc = fmaf(x[k], sW[k * D + d], acc);
    hbf[o] = f2bf(gelu_f(acc));
}

// dst[l*dstLS + n*dstRS + k] = bf16(src[l*srcLS + k*N + n])
__global__ __launch_bounds__(256) void transpose_cvt2_kernel(
    const float* __restrict__ src, u16* __restrict__ dst,
    int K, int N, int srcLS, int dstLS, int dstRS)
{
    int i = blockIdx.x * 256 + threadIdx.x;
    int per = K * N;
    int l = i / per;
    int r = i - l * per;
    int n = r / K;
    int k = r - n * K;
    dst[(size_t)l * dstLS + (size_t)n * dstRS + k] = f2bf(src[(size_t)l * srcLS + (size_t)k * N + n]);
}

// NW1T[l][n][128+k] = bf16( sum_j eW2[l][k][j] * uW1[l][128+j][n] )
__global__ __launch_bounds__(256) void w2p_kernel(
    const float* __restrict__ eW2, const float* __restrict__ uW1,
    u16* __restrict__ NW1T)
{
    int i = blockIdx.x * 256 + threadIdx.x;       // NL*128*128
    int l = i / 16384;
    int r = i - l * 16384;
    int n = r >> 7, k = r & 127;
    const float* w2row = eW2 + (size_t)l * 16384 + k * 128;
    const float* u1col = uW1 + (size_t)l * 32768 + 128 * 128 + n;
    float s = 0.f;
#pragma unroll 4
    for (int j = 0; j < 128; ++j) s = fmaf(w2row[j], u1col[j * 128], s);
    NW1T[(size_t)l * 32768 + n * 256 + 128 + k] = f2bf(s);
}

// nb2p[l][n] = sum_j eb2[l][j] * uW1[l][128+j][n]
__global__ __launch_bounds__(128) void b2p_kernel(
    const float* __restrict__ eb2, const float* __restrict__ uW1,
    float* __restrict__ nb2p)
{
    int l = blockIdx.x, n = threadIdx.x;
    const float* b2r = eb2 + l * 128;
    const float* u1col = uW1 + (size_t)l * 32768 + 128 * 128 + n;
    float s = 0.f;
#pragma unroll 4
    for (int j = 0; j < 128; ++j) s = fmaf(b2r[j], u1col[j * 128], s);
    nb2p[l * 128 + n] = s;
}

// P[n][0:256] = hbf[n] @ [W1a | W1b]   (64 nodes/block, 4 waves x 64 cols)
__global__ __launch_bounds__(256) void proj_kernel(
    const u16* __restrict__ hbf, const u16* __restrict__ PWT,
    u16* __restrict__ P)
{
    __shared__ u16 sA[64 * 136];
    const int tid = threadIdx.x;
    const int n0 = blockIdx.x * 64;
    {
        const int e = tid >> 2, q = tid & 3;      // 4 threads/row, 4 chunks each
        int n = n0 + e; if (n >= NN) n = NN - 1;
        const uint4* hs = (const uint4*)(hbf + (size_t)n * D);
        uint4* ar = (uint4*)(sA + e * 136);
#pragma unroll
        for (int c = 0; c < 4; ++c) ar[q * 4 + c] = hs[q * 4 + c];   // 16 chunks = full 128-elem row
    }
    __syncthreads();

    const int lane = tid & 63;
    const int l15 = lane & 15;
    const int quad = lane >> 4;
    const int nbase = (tid >> 6) * 64;

    f32x4 acc[4][4];
#pragma unroll
    for (int mt = 0; mt < 4; ++mt)
#pragma unroll
        for (int nt = 0; nt < 4; ++nt) acc[mt][nt] = (f32x4){0.f, 0.f, 0.f, 0.f};

#pragma unroll
    for (int kb = 0; kb < 128; kb += 32) {
        bf16x8 bf[4];
#pragma unroll
        for (int nt = 0; nt < 4; ++nt)
            bf[nt] = *(const bf16x8*)(PWT + (size_t)(nbase + nt * 16 + l15) * 128 + quad * 8 + kb);
#pragma unroll
        for (int mt = 0; mt < 4; ++mt) {
            bf16x8 af = *(const bf16x8*)(sA + (mt * 16 + l15) * 136 + quad * 8 + kb);
#pragma unroll
            for (int nt = 0; nt < 4; ++nt)
                acc[mt][nt] = __builtin_amdgcn_mfma_f32_16x16x32_bf16(af, bf[nt], acc[mt][nt], 0, 0, 0);
        }
    }

#pragma unroll
    for (int mt = 0; mt < 4; ++mt)
#pragma unroll
        for (int nt = 0; nt < 4; ++nt) {
            const int col = nbase + nt * 16 + l15;
#pragma unroll
            for (int r = 0; r < 4; ++r) {
                const int row = mt * 16 + quad * 4 + r;
                const int n = n0 + row;
                if (n < NN) P[(size_t)n * 256 + col] = f2bf(acc[mt][nt][r]);
            }
        }
}

// Elementwise edge pass over dst-sorted edges + segmented sum into S32.
// h1 = gelu(P1[src] + P2[dst] + ew*W1last + b1); S32[dst] += h1
#define EPB 1024
__global__ __launch_bounds__(256) void edge_pass_kernel(
    const u16* __restrict__ P, const int* __restrict__ sSrc,
    const int* __restrict__ sDst, const float* __restrict__ sEw,
    const float* __restrict__ W1last, const float* __restrict__ b1,
    float* __restrict__ S32)
{
    __shared__ int sS[EPB];
    __shared__ int sD[EPB];
    __shared__ float sE[EPB];
    const int tid = threadIdx.x;
    const int e0 = blockIdx.x * EPB;
    for (int i = tid; i < EPB; i += 256) {
        int e = e0 + i;
        bool v = e < NE;
        sS[i] = v ? sSrc[e] : 0;
        sD[i] = v ? sDst[e] : -1;
        sE[i] = v ? sEw[e] : 0.f;
    }
    __syncthreads();

    const int sub = tid & 15, grp = tid >> 4;     // 16 groups x 64 edges
    const int colb = sub * 8;
    float wl[8], bb[8];
    {
        float4 a0 = *(const float4*)(W1last + colb);
        float4 a1 = *(const float4*)(W1last + colb + 4);
        wl[0]=a0.x; wl[1]=a0.y; wl[2]=a0.z; wl[3]=a0.w;
        wl[4]=a1.x; wl[5]=a1.y; wl[6]=a1.z; wl[7]=a1.w;
        float4 c0 = *(const float4*)(b1 + colb);
        float4 c1 = *(const float4*)(b1 + colb + 4);
        bb[0]=c0.x; bb[1]=c0.y; bb[2]=c0.z; bb[3]=c0.w;
        bb[4]=c1.x; bb[5]=c1.y; bb[6]=c1.z; bb[7]=c1.w;
    }

    float acc[8], t2[8];
    int cur = -1;
    const int base = grp * 64;
    for (int i = 0; i < 64; ++i) {
        int d = sD[base + i];
        if (d < 0) break;
        if (d != cur) {
            if (cur >= 0) {
#pragma unroll
                for (int j = 0; j < 8; ++j)
                    atomicAdd(&S32[(size_t)cur * D + colb + j], acc[j]);
            }
            cur = d;
            uint4 p2 = *(const uint4*)(P + (size_t)d * 256 + 128 + colb);
            unpack8(p2, t2);
#pragma unroll
            for (int j = 0; j < 8; ++j) { t2[j] += bb[j]; acc[j] = 0.f; }
        }
        int s = sS[base + i];
        float w = sE[base + i];
        uint4 p1 = *(const uint4*)(P + (size_t)s * 256 + colb);
        float f[8];
        unpack8(p1, f);
#pragma unroll
        for (int j = 0; j < 8; ++j)
            acc[j] += gelu_f(f[j] + t2[j] + w * wl[j]);
    }
    if (cur >= 0) {
#pragma unroll
        for (int j = 0; j < 8; ++j)
            atomicAdd(&S32[(size_t)cur * D + colb + j], acc[j]);
    }
}

// Node update on MFMA: A=[hbf|S], W=[U1a;W2'], bias ub1+cnt*b2'; gelu; @U2;
// residual(hbf) + LayerNorm. 64 nodes/block.
__global__ __launch_bounds__(256, 3) void node_mfma_kernel(
    const u16* __restrict__ hbf, const float* __restrict__ S32,
    const int* __restrict__ hist,
    const u16* __restrict__ NW1T, const float* __restrict__ ub1,
    const float* __restrict__ nb2p,
    const u16* __restrict__ W2T, const float* __restrict__ b2,
    const float* __restrict__ gamma, const float* __restrict__ beta,
    float* __restrict__ hidden_out, u16* __restrict__ hbf_out)
{
    __shared__ u16 sA[64 * 264];
    __shared__ u16 sH1[64 * 136];
    __shared__ float s_cnt[64];
    float* sR = (float*)sA;
    const int tid = threadIdx.x;
    const int n0 = blockIdx.x * 64;

    if (tid < 64) {
        int n = n0 + tid; if (n >= NN) n = NN - 1;
        s_cnt[tid] = (float)hist[n];
    }
    {
        const int e = tid >> 2, q = tid & 3;
        int n = n0 + e; if (n >= NN) n = NN - 1;
        const uint4* hs = (const uint4*)(hbf + (size_t)n * D);
        const float4* ag = (const float4*)(S32 + (size_t)n * D);
        uint4* ar = (uint4*)(sA + e * 264);
#pragma unroll
        for (int c = 0; c < 8; ++c) {
            int cc = q * 8 + c;
            if (cc < 16) ar[cc] = hs[cc];
            else {
                float4 x0 = ag[(cc - 16) * 2];
                float4 x1 = ag[(cc - 16) * 2 + 1];
                uint4 p;
                p.x = (unsigned)f2bf(x0.x) | ((unsigned)f2bf(x0.y) << 16);
                p.y = (unsigned)f2bf(x0.z) | ((unsigned)f2bf(x0.w) << 16);
                p.z = (unsigned)f2bf(x1.x) | ((unsigned)f2bf(x1.y) << 16);
                p.w = (unsigned)f2bf(x1.z) | ((unsigned)f2bf(x1.w) << 16);
                ar[cc] = p;
            }
        }
    }
    __syncthreads();

    const int lane = tid & 63;
    const int l15 = lane & 15;
    const int quad = lane >> 4;
    const int nbase = (tid >> 6) * 32;

    f32x4 acc[4][2];
#pragma unroll
    for (int mt = 0; mt < 4; ++mt)
#pragma unroll
        for (int nt = 0; nt < 2; ++nt) acc[mt][nt] = (f32x4){0.f, 0.f, 0.f, 0.f};

    const u16* bp0 = NW1T + (size_t)(nbase + l15) * 256 + quad * 8;
    const u16* bp1 = bp0 + 16 * 256;
#pragma unroll
    for (int kb = 0; kb < 256; kb += 32) {
        bf16x8 bf0 = *(const bf16x8*)(bp0 + kb);
        bf16x8 bf1 = *(const bf16x8*)(bp1 + kb);
#pragma unroll
        for (int mt = 0; mt < 4; ++mt) {
            bf16x8 af = *(const bf16x8*)(sA + (mt * 16 + l15) * 264 + quad * 8 + kb);
            acc[mt][0] = __builtin_amdgcn_mfma_f32_16x16x32_bf16(af, bf0, acc[mt][0], 0, 0, 0);
            acc[mt][1] = __builtin_amdgcn_mfma_f32_16x16x32_bf16(af, bf1, acc[mt][1], 0, 0, 0);
        }
    }

    // epilogue 1: + ub1 + cnt*b2'; gelu -> sH1
#pragma unroll
    for (int mt = 0; mt < 4; ++mt)
#pragma unroll
        for (int nt = 0; nt < 2; ++nt) {
            const int col = nbase + nt * 16 + l15;
            const float bb = ub1[col];
            const float bp = nb2p[col];
#pragma unroll
            for (int r = 0; r < 4; ++r) {
                const int row = mt * 16 + quad * 4 + r;
                float v = acc[mt][nt][r] + bb + s_cnt[row] * bp;
                sH1[row * 136 + col] = f2bf(gelu_f(v));
            }
        }
    __syncthreads();

    f32x4 acc2[4][2];
#pragma unroll
    for (int mt = 0; mt < 4; ++mt)
#pragma unroll
        for (int nt = 0; nt < 2; ++nt) acc2[mt][nt] = (f32x4){0.f, 0.f, 0.f, 0.f};

    const u16* cp0 = W2T + (size_t)(nbase + l15) * 128 + quad * 8;
    const u16* cp1 = cp0 + 16 * 128;
#pragma unroll
    for (int kb = 0; kb < 128; kb += 32) {
        bf16x8 bf0 = *(const bf16x8*)(cp0 + kb);
        bf16x8 bf1 = *(const bf16x8*)(cp1 + kb);
#pragma unroll
        for (int mt = 0; mt < 4; ++mt) {
            bf16x8 af = *(const bf16x8*)(sH1 + (mt * 16 + l15) * 136 + quad * 8 + kb);
            acc2[mt][0] = __builtin_amdgcn_mfma_f32_16x16x32_bf16(af, bf0, acc2[mt][0], 0, 0, 0);
            acc2[mt][1] = __builtin_amdgcn_mfma_f32_16x16x32_bf16(af, bf1, acc2[mt][1], 0, 0, 0);
        }
    }

    // r = hbf + u -> sR (fp32)
#pragma unroll
    for (int mt = 0; mt < 4; ++mt)
#pragma unroll
        for (int nt = 0; nt < 2; ++nt) {
            const int col = nbase + nt * 16 + l15;
            const float bb = b2[col];
#pragma unroll
            for (int r = 0; r < 4; ++r) {
                const int row = mt * 16 + quad * 4 + r;
                int n = n0 + row; if (n >= NN) n = NN - 1;
                float h = __uint_as_float((unsigned)hbf[(size_t)n * D + col] << 16);
                sR[row * 132 + col] = acc2[mt][nt][r] + bb + h;
            }
        }
    __syncthreads();

    {
        const int e = tid >> 2, t4 = tid & 3;
        const int n = n0 + e;
        const float* rr = sR + e * 132 + t4 * 32;
        float s1 = 0.f, s2 = 0.f;
        float4 v[8];
#pragma unroll
        for (int i = 0; i < 8; ++i) {
            v[i] = *(const float4*)(rr + i * 4);
            s1 += v[i].x + v[i].y + v[i].z + v[i].w;
            s2 += v[i].x * v[i].x + v[i].y * v[i].y + v[i].z * v[i].z + v[i].w * v[i].w;
        }
        s1 += __shfl_xor(s1, 1); s2 += __shfl_xor(s2, 1);
        s1 += __shfl_xor(s1, 2); s2 += __shfl_xor(s2, 2);
        const float mean = s1 * (1.f / 128.f);
        const float var = s2 * (1.f / 128.f) - mean * mean;
        const float rs = rsqrtf(var + LN_EPS);
        if (n < NN) {
            float* op = hidden_out + (size_t)n * D + t4 * 32;
            u16* bp = hbf_out + (size_t)n * D + t4 * 32;
#pragma unroll
            for (int i = 0; i < 8; ++i) {
                const float4 g = *(const float4*)(gamma + t4 * 32 + i * 4);
                const float4 be = *(const float4*)(beta + t4 * 32 + i * 4);
                float4 o;
                o.x = (v[i].x - mean) * rs * g.x + be.x;
                o.y = (v[i].y - mean) * rs * g.y + be.y;
                o.z = (v[i].z - mean) * rs * g.z + be.z;
                o.w = (v[i].w - mean) * rs * g.w + be.w;
                *(float4*)(op + i * 4) = o;
                uint2 pk;
                pk.x = (unsigned)f2bf(o.x) | ((unsigned)f2bf(o.y) << 16);
                pk.y = (unsigned)f2bf(o.z) | ((unsigned)f2bf(o.w) << 16);
                *(uint2*)(bp + i * 4) = pk;
            }
        }
    }
}

// ---------------- pooling ----------------
__global__ __launch_bounds__(256) void count_kernel(
    const int* __restrict__ batch, float* __restrict__ counts)
{
    int t = blockIdx.x * 256 + threadIdx.x;
    const int chunk = (NN + 8191) / 8192;
    int beg = t * chunk, end = beg + chunk;
    if (end > NN) end = NN;
    if (beg >= NN) return;
    int cur = batch[beg];
    float cnt = 0.f;
    for (int i = beg; i < end; ++i) {
        int b = batch[i];
        if (b != cur) { atomicAdd(&counts[cur], cnt); cur = b; cnt = 0.f; }
        cnt += 1.f;
    }
    atomicAdd(&counts[cur], cnt);
}

__global__ __launch_bounds__(256) void pool_accum_kernel(
    const float* __restrict__ hidden, const int* __restrict__ batch,
    float* __restrict__ pooled)
{
    __shared__ int sb[128];
    const int n0 = blockIdx.x * 128;
    const int tid = threadIdx.x;
    if (tid < 128) sb[tid] = (n0 + tid < NN) ? batch[n0 + tid] : -1;
    __syncthreads();
    const int col = tid & 127, half = tid >> 7;
    const int base = half * 64;
    int cur = sb[base];
    float acc = 0.f;
    for (int i = 0; i < 64; ++i) {
        int n = n0 + base + i;
        if (n >= NN) break;
        int b = sb[base + i];
        if (b != cur) { atomicAdd(&pooled[cur * D + col], acc); cur = b; acc = 0.f; }
        acc += hidden[(size_t)n * D + col];
    }
    if (cur >= 0 && acc != 0.f) atomicAdd(&pooled[cur * D + col], acc);
}

__global__ __launch_bounds__(256) void pool_div_kernel(
    float* __restrict__ pooled, const float* __restrict__ counts)
{
    int i = blockIdx.x * 256 + threadIdx.x;
    pooled[i] /= fmaxf(counts[i >> 7], 1.0f);
}

extern "C" void kernel_launch(void* const* d_in, const int* in_sizes, int n_in,
                              void* d_out, int out_size, void* d_ws, size_t ws_size,
                              hipStream_t stream) {
    const float* X     = (const float*)d_in[0];
    const int*   eidx  = (const int*)d_in[1];
    const float* ew    = (const float*)d_in[2];
    const int*   batch = (const int*)d_in[3];
    const float* W_in  = (const float*)d_in[5];
    const float* b_in  = (const float*)d_in[6];
    const float* eW1   = (const float*)d_in[7];
    const float* eb1   = (const float*)d_in[8];
    const float* eW2   = (const float*)d_in[9];
    const float* eb2   = (const float*)d_in[10];
    const float* uW1   = (const float*)d_in[11];
    const float* ub1   = (const float*)d_in[12];
    const float* uW2   = (const float*)d_in[13];
    const float* ub2   = (const float*)d_in[14];
    const float* gamma = (const float*)d_in[15];
    const float* beta  = (const float*)d_in[16];

    float* out_hidden = (float*)d_out;
    float* out_pooled = out_hidden + (size_t)NN * D;

    u16*   hbf  = (u16*)d_ws;                                  // N*128 bf16
    u16*   P    = hbf + (size_t)NN * D;                        // N*256 bf16
    float* S32  = (float*)(P + (size_t)NN * 256);              // N*128 f32
    u16*   PWT  = (u16*)(S32 + (size_t)NN * D);                // NL*256*128
    u16*   NW1T = PWT + (size_t)NL * 256 * 128;                // NL*128*256
    u16*   uW2T = NW1T + (size_t)NL * 128 * 256;               // NL*128*128
    float* nb2p = (float*)(uW2T + (size_t)NL * 128 * 128);     // NL*128
    int*   hist   = (int*)(nb2p + (size_t)NL * 128);
    int*   cursor = hist + NN;
    int*   sSrc   = cursor + NN;
    int*   sDst   = sSrc + NE;
    float* sEw    = (float*)(sDst + NE);
    float* counts = sEw + NE;

    const int* src = eidx;
    const int* dst = eidx + NE;

    // edge sort by dst
    hipMemsetAsync(hist, 0, (size_t)NN * sizeof(int), stream);
    hist_kernel<<<NE / 256, 256, 0, stream>>>(dst, hist);
    scan_kernel<<<1, 1024, 0, stream>>>(hist, cursor);
    scatter_kernel<<<NE / 256, 256, 0, stream>>>(src, dst, ew, cursor, sSrc, sDst, sEw);

    // weight prep
    transpose_cvt2_kernel<<<192, 256, 0, stream>>>(eW1, PWT, 128, 128, 257 * 128, 256 * 128, 128);
    transpose_cvt2_kernel<<<192, 256, 0, stream>>>(eW1 + 128 * 128, PWT + 128 * 128, 128, 128, 257 * 128, 256 * 128, 128);
    transpose_cvt2_kernel<<<192, 256, 0, stream>>>(uW1, NW1T, 128, 128, 256 * 128, 128 * 256, 256);
    transpose_cvt2_kernel<<<192, 256, 0, stream>>>(uW2, uW2T, 128, 128, 128 * 128, 128 * 128, 128);
    w2p_kernel<<<192, 256, 0, stream>>>(eW2, uW1, NW1T);
    b2p_kernel<<<NL, 128, 0, stream>>>(eb2, uW1, nb2p);

    input_proj_kernel<<<(NN * D) / 256, 256, 0, stream>>>(X, W_in, b_in, hbf);

    const int nblk = (NN + 63) / 64;
    for (int l = 0; l < NL; ++l) {
        hipMemsetAsync(S32, 0, (size_t)NN * D * sizeof(float), stream);
        proj_kernel<<<nblk, 256, 0, stream>>>(hbf, PWT + (size_t)l * 256 * 128, P);
        edge_pass_kernel<<<(NE + EPB - 1) / EPB, 256, 0, stream>>>(
            P, sSrc, sDst, sEw,
            eW1 + (size_t)l * 257 * 128 + 256 * 128,   // W1 row k=256 (fp32)
            eb1 + (size_t)l * D, S32);
        node_mfma_kernel<<<nblk, 256, 0, stream>>>(
            hbf, S32, hist,
            NW1T + (size_t)l * 128 * 256, ub1 + (size_t)l * D, nb2p + (size_t)l * D,
            uW2T + (size_t)l * 128 * 128, ub2 + (size_t)l * D,
            gamma + (size_t)l * D, beta + (size_t)l * D,
            out_hidden, hbf);
    }

    hipMemsetAsync(out_pooled, 0, (size_t)NG * D * sizeof(float), stream);
    hipMemsetAsync(counts, 0, (size_t)NG * sizeof(float), stream);
    count_kernel<<<32, 256, 0, stream>>>(batch, counts);
    pool_accum_kernel<<<(NN + 127) / 128, 256, 0, stream>>>(out_hidden, batch, out_pooled);
    pool_div_kernel<<<(NG * D) / 256, 256, 0, stream>>>(out_pooled, counts);
}

// Round 6
// 924.564 us; speedup vs baseline: 1.4690x; 1.4690x over previous
//
#include <hip/hip_runtime.h>
#include <math.h>

#define NN 50000
#define NE 800000
#define DIN 32
#define D 128
#define NL 3
#define NG 64
#define LN_EPS 1e-5f

typedef unsigned short u16;
typedef __bf16 bf16x8 __attribute__((ext_vector_type(8)));
typedef float f32x4 __attribute__((ext_vector_type(4)));

__device__ __forceinline__ float gelu_f(float x) {
    return 0.5f * x * (1.0f + erff(x * 0.70710678118654752f));
}

__device__ __forceinline__ u16 f2bf(float x) {
    unsigned int u = __float_as_uint(x);
    u += 0x7fffu + ((u >> 16) & 1u);
    return (u16)(u >> 16);
}

// ---------------- counting sort of edges by dst ----------------
__global__ __launch_bounds__(256) void hist_kernel(
    const int* __restrict__ dst, int* __restrict__ hist)
{
    int e = blockIdx.x * 256 + threadIdx.x;
    atomicAdd(&hist[dst[e]], 1);
}

// exclusive scan over NN bins -> row_ptr (immutable) + cursor (scatter mutable)
__global__ __launch_bounds__(1024) void scan_kernel(
    const int* __restrict__ hist, int* __restrict__ row_ptr, int* __restrict__ cursor)
{
    __shared__ int part[1024];
    const int t = threadIdx.x;
    const int CH = (NN + 1023) / 1024;
    int beg = t * CH, end = beg + CH;
    if (end > NN) end = NN;
    int s = 0;
    for (int i = beg; i < end; ++i) s += hist[i];
    part[t] = s;
    __syncthreads();
    for (int off = 1; off < 1024; off <<= 1) {
        int v = (t >= off) ? part[t - off] : 0;
        __syncthreads();
        part[t] += v;
        __syncthreads();
    }
    int run = (t > 0) ? part[t - 1] : 0;
    for (int i = beg; i < end; ++i) {
        row_ptr[i] = run;
        cursor[i] = run;
        run += hist[i];
    }
    if (t == 1023) row_ptr[NN] = NE;   // run of last non-empty chunk sums to NE
}

__global__ __launch_bounds__(256) void scatter_kernel(
    const int* __restrict__ src, const int* __restrict__ dst,
    const float* __restrict__ ew, int* __restrict__ cursor,
    int* __restrict__ sSrc, float* __restrict__ sEw)
{
    int e = blockIdx.x * 256 + threadIdx.x;
    int d = dst[e];
    int pos = atomicAdd(&cursor[d], 1);
    sSrc[pos] = src[e];
    sEw[pos] = ew[e];
}

// ---------------- projections / weight prep ----------------
__global__ __launch_bounds__(256) void input_proj_kernel(
    const float* __restrict__ X, const float* __restrict__ W,
    const float* __restrict__ b, u16* __restrict__ hbf)
{
    __shared__ float sW[DIN * D];
    for (int i = threadIdx.x; i < DIN * D; i += 256) sW[i] = W[i];
    __syncthreads();
    int o = blockIdx.x * 256 + threadIdx.x;
    int n = o >> 7, d = o & 127;
    const float* x = X + n * DIN;
    float acc = b[d];
#pragma unroll
    for (int k = 0; k < DIN; ++k) acc = fmaf(x[k], sW[k * D + d], acc);
    hbf[o] = f2bf(gelu_f(acc));
}

// dst[l*dstLS + n*dstRS + k] = bf16(src[l*srcLS + k*N + n])
__global__ __launch_bounds__(256) void transpose_cvt2_kernel(
    const float* __restrict__ src, u16* __restrict__ dst,
    int K, int N, int srcLS, int dstLS, int dstRS)
{
    int i = blockIdx.x * 256 + threadIdx.x;
    int per = K * N;
    int l = i / per;
    int r = i - l * per;
    int n = r / K;
    int k = r - n * K;
    dst[(size_t)l * dstLS + (size_t)n * dstRS + k] = f2bf(src[(size_t)l * srcLS + (size_t)k * N + n]);
}

// NW1T[l][n][128+k] = bf16( sum_j eW2[l][k][j] * uW1[l][128+j][n] )
__global__ __launch_bounds__(256) void w2p_kernel(
    const float* __restrict__ eW2, const float* __restrict__ uW1,
    u16* __restrict__ NW1T)
{
    int i = blockIdx.x * 256 + threadIdx.x;       // NL*128*128
    int l = i / 16384;
    int r = i - l * 16384;
    int n = r >> 7, k = r & 127;
    const float* w2row = eW2 + (size_t)l * 16384 + k * 128;
    const float* u1col = uW1 + (size_t)l * 32768 + 128 * 128 + n;
    float s = 0.f;
#pragma unroll 4
    for (int j = 0; j < 128; ++j) s = fmaf(w2row[j], u1col[j * 128], s);
    NW1T[(size_t)l * 32768 + n * 256 + 128 + k] = f2bf(s);
}

// nb2p[l][n] = sum_j eb2[l][j] * uW1[l][128+j][n]
__global__ __launch_bounds__(128) void b2p_kernel(
    const float* __restrict__ eb2, const float* __restrict__ uW1,
    float* __restrict__ nb2p)
{
    int l = blockIdx.x, n = threadIdx.x;
    const float* b2r = eb2 + l * 128;
    const float* u1col = uW1 + (size_t)l * 32768 + 128 * 128 + n;
    float s = 0.f;
#pragma unroll 4
    for (int j = 0; j < 128; ++j) s = fmaf(b2r[j], u1col[j * 128], s);
    nb2p[l * 128 + n] = s;
}

// P[n][0:256] = hbf[n] @ [W1a | W1b]   (64 nodes/block, 4 waves x 64 cols)
__global__ __launch_bounds__(256) void proj_kernel(
    const u16* __restrict__ hbf, const u16* __restrict__ PWT,
    u16* __restrict__ P)
{
    __shared__ u16 sA[64 * 136];
    const int tid = threadIdx.x;
    const int n0 = blockIdx.x * 64;
    {
        const int e = tid >> 2, q = tid & 3;      // 4 threads/row, 4 chunks each
        int n = n0 + e; if (n >= NN) n = NN - 1;
        const uint4* hs = (const uint4*)(hbf + (size_t)n * D);
        uint4* ar = (uint4*)(sA + e * 136);
#pragma unroll
        for (int c = 0; c < 4; ++c) ar[q * 4 + c] = hs[q * 4 + c];
    }
    __syncthreads();

    const int lane = tid & 63;
    const int l15 = lane & 15;
    const int quad = lane >> 4;
    const int nbase = (tid >> 6) * 64;

    f32x4 acc[4][4];
#pragma unroll
    for (int mt = 0; mt < 4; ++mt)
#pragma unroll
        for (int nt = 0; nt < 4; ++nt) acc[mt][nt] = (f32x4){0.f, 0.f, 0.f, 0.f};

#pragma unroll
    for (int kb = 0; kb < 128; kb += 32) {
        bf16x8 bf[4];
#pragma unroll
        for (int nt = 0; nt < 4; ++nt)
            bf[nt] = *(const bf16x8*)(PWT + (size_t)(nbase + nt * 16 + l15) * 128 + quad * 8 + kb);
#pragma unroll
        for (int mt = 0; mt < 4; ++mt) {
            bf16x8 af = *(const bf16x8*)(sA + (mt * 16 + l15) * 136 + quad * 8 + kb);
#pragma unroll
            for (int nt = 0; nt < 4; ++nt)
                acc[mt][nt] = __builtin_amdgcn_mfma_f32_16x16x32_bf16(af, bf[nt], acc[mt][nt], 0, 0, 0);
        }
    }

#pragma unroll
    for (int mt = 0; mt < 4; ++mt)
#pragma unroll
        for (int nt = 0; nt < 4; ++nt) {
            const int col = nbase + nt * 16 + l15;
#pragma unroll
            for (int r = 0; r < 4; ++r) {
                const int row = mt * 16 + quad * 4 + r;
                const int n = n0 + row;
                if (n < NN) P[(size_t)n * 256 + col] = f2bf(acc[mt][nt][r]);
            }
        }
}

// CSR edge pass: one wave per dst node, lane owns 2 cols. Zero atomics.
// S32[n] = sum_{e in in-edges(n)} gelu(P1[src_e] + P2[n] + ew_e*W1last + b1)
__global__ __launch_bounds__(256) void edge_csr_kernel(
    const u16* __restrict__ P, const int* __restrict__ sSrc,
    const float* __restrict__ sEw, const int* __restrict__ row_ptr,
    const float* __restrict__ W1last, const float* __restrict__ b1,
    float* __restrict__ S32)
{
    const int n = (blockIdx.x * 256 + threadIdx.x) >> 6;   // node = global wave id
    if (n >= NN) return;
    const int lane = threadIdx.x & 63;
    const int c2 = lane * 2;

    const float wl0 = W1last[c2], wl1 = W1last[c2 + 1];
    unsigned p2 = *(const unsigned*)(P + (size_t)n * 256 + 128 + c2);
    const float t20 = __uint_as_float(p2 << 16) + b1[c2];
    const float t21 = __uint_as_float(p2 & 0xffff0000u) + b1[c2 + 1];

    float a0 = 0.f, a1 = 0.f;
    const int beg = row_ptr[n], end = row_ptr[n + 1];
    for (int e = beg; e < end; ++e) {
        const int s = sSrc[e];             // wave-uniform broadcast
        const float w = sEw[e];
        unsigned p1 = *(const unsigned*)(P + (size_t)s * 256 + c2);   // 256B/wave coalesced
        float f0 = __uint_as_float(p1 << 16);
        float f1 = __uint_as_float(p1 & 0xffff0000u);
        a0 += gelu_f(f0 + t20 + w * wl0);
        a1 += gelu_f(f1 + t21 + w * wl1);
    }
    float2 o; o.x = a0; o.y = a1;
    *(float2*)(S32 + (size_t)n * D + c2) = o;
}

// Node update on MFMA: A=[hbf|S], W=[U1a;W2'], bias ub1+cnt*b2'; gelu; @U2;
// residual(hbf) + LayerNorm. 64 nodes/block.
__global__ __launch_bounds__(256, 3) void node_mfma_kernel(
    const u16* __restrict__ hbf, const float* __restrict__ S32,
    const int* __restrict__ hist,
    const u16* __restrict__ NW1T, const float* __restrict__ ub1,
    const float* __restrict__ nb2p,
    const u16* __restrict__ W2T, const float* __restrict__ b2,
    const float* __restrict__ gamma, const float* __restrict__ beta,
    float* __restrict__ hidden_out, u16* __restrict__ hbf_out)
{
    __shared__ u16 sA[64 * 264];
    __shared__ u16 sH1[64 * 136];
    __shared__ float s_cnt[64];
    float* sR = (float*)sA;
    const int tid = threadIdx.x;
    const int n0 = blockIdx.x * 64;

    if (tid < 64) {
        int n = n0 + tid; if (n >= NN) n = NN - 1;
        s_cnt[tid] = (float)hist[n];
    }
    {
        const int e = tid >> 2, q = tid & 3;
        int n = n0 + e; if (n >= NN) n = NN - 1;
        const uint4* hs = (const uint4*)(hbf + (size_t)n * D);
        const float4* ag = (const float4*)(S32 + (size_t)n * D);
        uint4* ar = (uint4*)(sA + e * 264);
#pragma unroll
        for (int c = 0; c < 8; ++c) {
            int cc = q * 8 + c;
            if (cc < 16) ar[cc] = hs[cc];
            else {
                float4 x0 = ag[(cc - 16) * 2];
                float4 x1 = ag[(cc - 16) * 2 + 1];
                uint4 p;
                p.x = (unsigned)f2bf(x0.x) | ((unsigned)f2bf(x0.y) << 16);
                p.y = (unsigned)f2bf(x0.z) | ((unsigned)f2bf(x0.w) << 16);
                p.z = (unsigned)f2bf(x1.x) | ((unsigned)f2bf(x1.y) << 16);
                p.w = (unsigned)f2bf(x1.z) | ((unsigned)f2bf(x1.w) << 16);
                ar[cc] = p;
            }
        }
    }
    __syncthreads();

    const int lane = tid & 63;
    const int l15 = lane & 15;
    const int quad = lane >> 4;
    const int nbase = (tid >> 6) * 32;

    f32x4 acc[4][2];
#pragma unroll
    for (int mt = 0; mt < 4; ++mt)
#pragma unroll
        for (int nt = 0; nt < 2; ++nt) acc[mt][nt] = (f32x4){0.f, 0.f, 0.f, 0.f};

    const u16* bp0 = NW1T + (size_t)(nbase + l15) * 256 + quad * 8;
    const u16* bp1 = bp0 + 16 * 256;
#pragma unroll
    for (int kb = 0; kb < 256; kb += 32) {
        bf16x8 bf0 = *(const bf16x8*)(bp0 + kb);
        bf16x8 bf1 = *(const bf16x8*)(bp1 + kb);
#pragma unroll
        for (int mt = 0; mt < 4; ++mt) {
            bf16x8 af = *(const bf16x8*)(sA + (mt * 16 + l15) * 264 + quad * 8 + kb);
            acc[mt][0] = __builtin_amdgcn_mfma_f32_16x16x32_bf16(af, bf0, acc[mt][0], 0, 0, 0);
            acc[mt][1] = __builtin_amdgcn_mfma_f32_16x16x32_bf16(af, bf1, acc[mt][1], 0, 0, 0);
        }
    }

    // epilogue 1: + ub1 + cnt*b2'; gelu -> sH1
#pragma unroll
    for (int mt = 0; mt < 4; ++mt)
#pragma unroll
        for (int nt = 0; nt < 2; ++nt) {
            const int col = nbase + nt * 16 + l15;
            const float bb = ub1[col];
            const float bp = nb2p[col];
#pragma unroll
            for (int r = 0; r < 4; ++r) {
                const int row = mt * 16 + quad * 4 + r;
                float v = acc[mt][nt][r] + bb + s_cnt[row] * bp;
                sH1[row * 136 + col] = f2bf(gelu_f(v));
            }
        }
    __syncthreads();

    f32x4 acc2[4][2];
#pragma unroll
    for (int mt = 0; mt < 4; ++mt)
#pragma unroll
        for (int nt = 0; nt < 2; ++nt) acc2[mt][nt] = (f32x4){0.f, 0.f, 0.f, 0.f};

    const u16* cp0 = W2T + (size_t)(nbase + l15) * 128 + quad * 8;
    const u16* cp1 = cp0 + 16 * 128;
#pragma unroll
    for (int kb = 0; kb < 128; kb += 32) {
        bf16x8 bf0 = *(const bf16x8*)(cp0 + kb);
        bf16x8 bf1 = *(const bf16x8*)(cp1 + kb);
#pragma unroll
        for (int mt = 0; mt < 4; ++mt) {
            bf16x8 af = *(const bf16x8*)(sH1 + (mt * 16 + l15) * 136 + quad * 8 + kb);
            acc2[mt][0] = __builtin_amdgcn_mfma_f32_16x16x32_bf16(af, bf0, acc2[mt][0], 0, 0, 0);
            acc2[mt][1] = __builtin_amdgcn_mfma_f32_16x16x32_bf16(af, bf1, acc2[mt][1], 0, 0, 0);
        }
    }

    // r = hbf + u -> sR (fp32)
#pragma unroll
    for (int mt = 0; mt < 4; ++mt)
#pragma unroll
        for (int nt = 0; nt < 2; ++nt) {
            const int col = nbase + nt * 16 + l15;
            const float bb = b2[col];
#pragma unroll
            for (int r = 0; r < 4; ++r) {
                const int row = mt * 16 + quad * 4 + r;
                int n = n0 + row; if (n >= NN) n = NN - 1;
                float h = __uint_as_float((unsigned)hbf[(size_t)n * D + col] << 16);
                sR[row * 132 + col] = acc2[mt][nt][r] + bb + h;
            }
        }
    __syncthreads();

    {
        const int e = tid >> 2, t4 = tid & 3;
        const int n = n0 + e;
        const float* rr = sR + e * 132 + t4 * 32;
        float s1 = 0.f, s2 = 0.f;
        float4 v[8];
#pragma unroll
        for (int i = 0; i < 8; ++i) {
            v[i] = *(const float4*)(rr + i * 4);
            s1 += v[i].x + v[i].y + v[i].z + v[i].w;
            s2 += v[i].x * v[i].x + v[i].y * v[i].y + v[i].z * v[i].z + v[i].w * v[i].w;
        }
        s1 += __shfl_xor(s1, 1); s2 += __shfl_xor(s2, 1);
        s1 += __shfl_xor(s1, 2); s2 += __shfl_xor(s2, 2);
        const float mean = s1 * (1.f / 128.f);
        const float var = s2 * (1.f / 128.f) - mean * mean;
        const float rs = rsqrtf(var + LN_EPS);
        if (n < NN) {
            float* op = hidden_out + (size_t)n * D + t4 * 32;
            u16* bp = hbf_out + (size_t)n * D + t4 * 32;
#pragma unroll
            for (int i = 0; i < 8; ++i) {
                const float4 g = *(const float4*)(gamma + t4 * 32 + i * 4);
                const float4 be = *(const float4*)(beta + t4 * 32 + i * 4);
                float4 o;
                o.x = (v[i].x - mean) * rs * g.x + be.x;
                o.y = (v[i].y - mean) * rs * g.y + be.y;
                o.z = (v[i].z - mean) * rs * g.z + be.z;
                o.w = (v[i].w - mean) * rs * g.w + be.w;
                *(float4*)(op + i * 4) = o;
                uint2 pk;
                pk.x = (unsigned)f2bf(o.x) | ((unsigned)f2bf(o.y) << 16);
                pk.y = (unsigned)f2bf(o.z) | ((unsigned)f2bf(o.w) << 16);
                *(uint2*)(bp + i * 4) = pk;
            }
        }
    }
}

// ---------------- pooling ----------------
__global__ __launch_bounds__(256) void count_kernel(
    const int* __restrict__ batch, float* __restrict__ counts)
{
    int t = blockIdx.x * 256 + threadIdx.x;
    const int chunk = (NN + 8191) / 8192;
    int beg = t * chunk, end = beg + chunk;
    if (end > NN) end = NN;
    if (beg >= NN) return;
    int cur = batch[beg];
    float cnt = 0.f;
    for (int i = beg; i < end; ++i) {
        int b = batch[i];
        if (b != cur) { atomicAdd(&counts[cur], cnt); cur = b; cnt = 0.f; }
        cnt += 1.f;
    }
    atomicAdd(&counts[cur], cnt);
}

__global__ __launch_bounds__(256) void pool_accum_kernel(
    const float* __restrict__ hidden, const int* __restrict__ batch,
    float* __restrict__ pooled)
{
    __shared__ int sb[128];
    const int n0 = blockIdx.x * 128;
    const int tid = threadIdx.x;
    if (tid < 128) sb[tid] = (n0 + tid < NN) ? batch[n0 + tid] : -1;
    __syncthreads();
    const int col = tid & 127, half = tid >> 7;
    const int base = half * 64;
    int cur = sb[base];
    float acc = 0.f;
    for (int i = 0; i < 64; ++i) {
        int n = n0 + base + i;
        if (n >= NN) break;
        int b = sb[base + i];
        if (b != cur) { atomicAdd(&pooled[cur * D + col], acc); cur = b; acc = 0.f; }
        acc += hidden[(size_t)n * D + col];
    }
    if (cur >= 0 && acc != 0.f) atomicAdd(&pooled[cur * D + col], acc);
}

__global__ __launch_bounds__(256) void pool_div_kernel(
    float* __restrict__ pooled, const float* __restrict__ counts)
{
    int i = blockIdx.x * 256 + threadIdx.x;
    pooled[i] /= fmaxf(counts[i >> 7], 1.0f);
}

extern "C" void kernel_launch(void* const* d_in, const int* in_sizes, int n_in,
                              void* d_out, int out_size, void* d_ws, size_t ws_size,
                              hipStream_t stream) {
    const float* X     = (const float*)d_in[0];
    const int*   eidx  = (const int*)d_in[1];
    const float* ew    = (const float*)d_in[2];
    const int*   batch = (const int*)d_in[3];
    const float* W_in  = (const float*)d_in[5];
    const float* b_in  = (const float*)d_in[6];
    const float* eW1   = (const float*)d_in[7];
    const float* eb1   = (const float*)d_in[8];
    const float* eW2   = (const float*)d_in[9];
    const float* eb2   = (const float*)d_in[10];
    const float* uW1   = (const float*)d_in[11];
    const float* ub1   = (const float*)d_in[12];
    const float* uW2   = (const float*)d_in[13];
    const float* ub2   = (const float*)d_in[14];
    const float* gamma = (const float*)d_in[15];
    const float* beta  = (const float*)d_in[16];

    float* out_hidden = (float*)d_out;
    float* out_pooled = out_hidden + (size_t)NN * D;

    u16*   hbf  = (u16*)d_ws;                                  // N*128 bf16
    u16*   P    = hbf + (size_t)NN * D;                        // N*256 bf16
    float* S32  = (float*)(P + (size_t)NN * 256);              // N*128 f32
    u16*   PWT  = (u16*)(S32 + (size_t)NN * D);                // NL*256*128
    u16*   NW1T = PWT + (size_t)NL * 256 * 128;                // NL*128*256
    u16*   uW2T = NW1T + (size_t)NL * 128 * 256;               // NL*128*128
    float* nb2p = (float*)(uW2T + (size_t)NL * 128 * 128);     // NL*128
    int*   hist    = (int*)(nb2p + (size_t)NL * 128);
    int*   row_ptr = hist + NN;                                // NN+1 ints
    int*   cursor  = row_ptr + NN + 1;
    int*   sSrc    = cursor + NN;
    float* sEw     = (float*)(sSrc + NE);
    float* counts  = sEw + NE;

    const int* src = eidx;
    const int* dst = eidx + NE;

    // edge sort by dst (CSR build)
    hipMemsetAsync(hist, 0, (size_t)NN * sizeof(int), stream);
    hist_kernel<<<NE / 256, 256, 0, stream>>>(dst, hist);
    scan_kernel<<<1, 1024, 0, stream>>>(hist, row_ptr, cursor);
    scatter_kernel<<<NE / 256, 256, 0, stream>>>(src, dst, ew, cursor, sSrc, sEw);

    // weight prep
    transpose_cvt2_kernel<<<192, 256, 0, stream>>>(eW1, PWT, 128, 128, 257 * 128, 256 * 128, 128);
    transpose_cvt2_kernel<<<192, 256, 0, stream>>>(eW1 + 128 * 128, PWT + 128 * 128, 128, 128, 257 * 128, 256 * 128, 128);
    transpose_cvt2_kernel<<<192, 256, 0, stream>>>(uW1, NW1T, 128, 128, 256 * 128, 128 * 256, 256);
    transpose_cvt2_kernel<<<192, 256, 0, stream>>>(uW2, uW2T, 128, 128, 128 * 128, 128 * 128, 128);
    w2p_kernel<<<192, 256, 0, stream>>>(eW2, uW1, NW1T);
    b2p_kernel<<<NL, 128, 0, stream>>>(eb2, uW1, nb2p);

    input_proj_kernel<<<(NN * D) / 256, 256, 0, stream>>>(X, W_in, b_in, hbf);

    const int nblk = (NN + 63) / 64;
    for (int l = 0; l < NL; ++l) {
        proj_kernel<<<nblk, 256, 0, stream>>>(hbf, PWT + (size_t)l * 256 * 128, P);
        edge_csr_kernel<<<(NN * 64 + 255) / 256, 256, 0, stream>>>(
            P, sSrc, sEw, row_ptr,
            eW1 + (size_t)l * 257 * 128 + 256 * 128,   // W1 row k=256 (fp32)
            eb1 + (size_t)l * D, S32);
        node_mfma_kernel<<<nblk, 256, 0, stream>>>(
            hbf, S32, hist,
            NW1T + (size_t)l * 128 * 256, ub1 + (size_t)l * D, nb2p + (size_t)l * D,
            uW2T + (size_t)l * 128 * 128, ub2 + (size_t)l * D,
            gamma + (size_t)l * D, beta + (size_t)l * D,
            out_hidden, hbf);
    }

    hipMemsetAsync(out_pooled, 0, (size_t)NG * D * sizeof(float), stream);
    hipMemsetAsync(counts, 0, (size_t)NG * sizeof(float), stream);
    count_kernel<<<32, 256, 0, stream>>>(batch, counts);
    pool_accum_kernel<<<(NN + 127) / 128, 256, 0, stream>>>(out_hidden, batch, out_pooled);
    pool_div_kernel<<<(NG * D) / 256, 256, 0, stream>>>(out_pooled, counts);
}

// Round 7
// 723.463 us; speedup vs baseline: 1.8773x; 1.2780x over previous
//
#include <hip/hip_runtime.h>
#include <math.h>

#define NN 50000
#define NE 800000
#define DIN 32
#define D 128
#define NL 3
#define NG 64
#define LN_EPS 1e-5f
#define SCAN_BLOCKS 196   // ceil(NN/256)

typedef unsigned short u16;
typedef __bf16 bf16x8 __attribute__((ext_vector_type(8)));
typedef float f32x4 __attribute__((ext_vector_type(4)));

__device__ __forceinline__ float gelu_f(float x) {
    return 0.5f * x * (1.0f + erff(x * 0.70710678118654752f));
}

__device__ __forceinline__ u16 f2bf(float x) {
    unsigned int u = __float_as_uint(x);
    u += 0x7fffu + ((u >> 16) & 1u);
    return (u16)(u >> 16);
}

// ---------------- CSR build: hist + 2-level scan + scatter ----------------
__global__ __launch_bounds__(256) void hist_kernel(
    const int* __restrict__ dst, int* __restrict__ hist)
{
    int e = blockIdx.x * 256 + threadIdx.x;
    atomicAdd(&hist[dst[e]], 1);
}

__global__ __launch_bounds__(256) void bsum_kernel(
    const int* __restrict__ hist, int* __restrict__ bsum)
{
    __shared__ int red[256];
    int i = blockIdx.x * 256 + threadIdx.x;
    red[threadIdx.x] = (i < NN) ? hist[i] : 0;
    __syncthreads();
    for (int off = 128; off > 0; off >>= 1) {
        if (threadIdx.x < off) red[threadIdx.x] += red[threadIdx.x + off];
        __syncthreads();
    }
    if (threadIdx.x == 0) bsum[blockIdx.x] = red[0];
}

__global__ __launch_bounds__(256) void bscan_kernel(
    const int* __restrict__ bsum, int* __restrict__ boff)
{
    __shared__ int sc[256];
    const int t = threadIdx.x;
    int orig = (t < SCAN_BLOCKS) ? bsum[t] : 0;
    sc[t] = orig;
    __syncthreads();
    for (int off = 1; off < 256; off <<= 1) {
        int v = (t >= off) ? sc[t - off] : 0;
        __syncthreads();
        sc[t] += v;
        __syncthreads();
    }
    if (t < SCAN_BLOCKS) boff[t] = sc[t] - orig;   // exclusive
}

__global__ __launch_bounds__(256) void emit_kernel(
    const int* __restrict__ hist, const int* __restrict__ boff,
    int* __restrict__ row_ptr, int* __restrict__ cursor)
{
    __shared__ int sc[256];
    const int t = threadIdx.x;
    const int i = blockIdx.x * 256 + t;
    int orig = (i < NN) ? hist[i] : 0;
    sc[t] = orig;
    __syncthreads();
    for (int off = 1; off < 256; off <<= 1) {
        int v = (t >= off) ? sc[t - off] : 0;
        __syncthreads();
        sc[t] += v;
        __syncthreads();
    }
    if (i < NN) {
        int ex = sc[t] - orig + boff[blockIdx.x];
        row_ptr[i] = ex;
        cursor[i] = ex;
    }
    if (i == 0) row_ptr[NN] = NE;
}

__global__ __launch_bounds__(256) void scatter_kernel(
    const int* __restrict__ src, const int* __restrict__ dst,
    const float* __restrict__ ew, int* __restrict__ cursor,
    int* __restrict__ sSrc, float* __restrict__ sEw)
{
    int e = blockIdx.x * 256 + threadIdx.x;
    int d = dst[e];
    int pos = atomicAdd(&cursor[d], 1);
    sSrc[pos] = src[e];
    sEw[pos] = ew[e];
}

// ---------------- projections / weight prep ----------------
__global__ __launch_bounds__(256) void input_proj_kernel(
    const float* __restrict__ X, const float* __restrict__ W,
    const float* __restrict__ b, u16* __restrict__ hbf)
{
    __shared__ float sW[DIN * D];
    for (int i = threadIdx.x; i < DIN * D; i += 256) sW[i] = W[i];
    __syncthreads();
    int o = blockIdx.x * 256 + threadIdx.x;
    int n = o >> 7, d = o & 127;
    const float* x = X + n * DIN;
    float acc = b[d];
#pragma unroll
    for (int k = 0; k < DIN; ++k) acc = fmaf(x[k], sW[k * D + d], acc);
    hbf[o] = f2bf(gelu_f(acc));
}

// dst[l*dstLS + n*dstRS + k] = bf16(src[l*srcLS + k*N + n])
__global__ __launch_bounds__(256) void transpose_cvt2_kernel(
    const float* __restrict__ src, u16* __restrict__ dst,
    int K, int N, int srcLS, int dstLS, int dstRS)
{
    int i = blockIdx.x * 256 + threadIdx.x;
    int per = K * N;
    int l = i / per;
    int r = i - l * per;
    int n = r / K;
    int k = r - n * K;
    dst[(size_t)l * dstLS + (size_t)n * dstRS + k] = f2bf(src[(size_t)l * srcLS + (size_t)k * N + n]);
}

// NW1T[l][n][128+k] = bf16( sum_j eW2[l][k][j] * uW1[l][128+j][n] )
__global__ __launch_bounds__(256) void w2p_kernel(
    const float* __restrict__ eW2, const float* __restrict__ uW1,
    u16* __restrict__ NW1T)
{
    int i = blockIdx.x * 256 + threadIdx.x;       // NL*128*128
    int l = i / 16384;
    int r = i - l * 16384;
    int n = r >> 7, k = r & 127;
    const float* w2row = eW2 + (size_t)l * 16384 + k * 128;
    const float* u1col = uW1 + (size_t)l * 32768 + 128 * 128 + n;
    float s = 0.f;
#pragma unroll 4
    for (int j = 0; j < 128; ++j) s = fmaf(w2row[j], u1col[j * 128], s);
    NW1T[(size_t)l * 32768 + n * 256 + 128 + k] = f2bf(s);
}

// nb2p[l][n] = sum_j eb2[l][j] * uW1[l][128+j][n]
__global__ __launch_bounds__(128) void b2p_kernel(
    const float* __restrict__ eb2, const float* __restrict__ uW1,
    float* __restrict__ nb2p)
{
    int l = blockIdx.x, n = threadIdx.x;
    const float* b2r = eb2 + l * 128;
    const float* u1col = uW1 + (size_t)l * 32768 + 128 * 128 + n;
    float s = 0.f;
#pragma unroll 4
    for (int j = 0; j < 128; ++j) s = fmaf(b2r[j], u1col[j * 128], s);
    nb2p[l * 128 + n] = s;
}

// P[n][0:256] = hbf[n] @ [W1a | W1b]   (layer-0 only; later layers fused into node)
__global__ __launch_bounds__(256) void proj_kernel(
    const u16* __restrict__ hbf, const u16* __restrict__ PWT,
    u16* __restrict__ P)
{
    __shared__ u16 sA[64 * 136];
    const int tid = threadIdx.x;
    const int n0 = blockIdx.x * 64;
    {
        const int e = tid >> 2, q = tid & 3;
        int n = n0 + e; if (n >= NN) n = NN - 1;
        const uint4* hs = (const uint4*)(hbf + (size_t)n * D);
        uint4* ar = (uint4*)(sA + e * 136);
#pragma unroll
        for (int c = 0; c < 4; ++c) ar[q * 4 + c] = hs[q * 4 + c];
    }
    __syncthreads();

    const int lane = tid & 63;
    const int l15 = lane & 15;
    const int quad = lane >> 4;
    const int nbase = (tid >> 6) * 64;

    f32x4 acc[4][4];
#pragma unroll
    for (int mt = 0; mt < 4; ++mt)
#pragma unroll
        for (int nt = 0; nt < 4; ++nt) acc[mt][nt] = (f32x4){0.f, 0.f, 0.f, 0.f};

#pragma unroll
    for (int kb = 0; kb < 128; kb += 32) {
        bf16x8 bf[4];
#pragma unroll
        for (int nt = 0; nt < 4; ++nt)
            bf[nt] = *(const bf16x8*)(PWT + (size_t)(nbase + nt * 16 + l15) * 128 + quad * 8 + kb);
#pragma unroll
        for (int mt = 0; mt < 4; ++mt) {
            bf16x8 af = *(const bf16x8*)(sA + (mt * 16 + l15) * 136 + quad * 8 + kb);
#pragma unroll
            for (int nt = 0; nt < 4; ++nt)
                acc[mt][nt] = __builtin_amdgcn_mfma_f32_16x16x32_bf16(af, bf[nt], acc[mt][nt], 0, 0, 0);
        }
    }

#pragma unroll
    for (int mt = 0; mt < 4; ++mt)
#pragma unroll
        for (int nt = 0; nt < 4; ++nt) {
            const int col = nbase + nt * 16 + l15;
#pragma unroll
            for (int r = 0; r < 4; ++r) {
                const int row = mt * 16 + quad * 4 + r;
                const int n = n0 + row;
                if (n < NN) P[(size_t)n * 256 + col] = f2bf(acc[mt][nt][r]);
            }
        }
}

// CSR edge pass: one wave per dst node, lane owns 2 cols. Zero atomics.
__global__ __launch_bounds__(256) void edge_csr_kernel(
    const u16* __restrict__ P, const int* __restrict__ sSrc,
    const float* __restrict__ sEw, const int* __restrict__ row_ptr,
    const float* __restrict__ W1last, const float* __restrict__ b1,
    float* __restrict__ S32)
{
    const int n = (blockIdx.x * 256 + threadIdx.x) >> 6;
    if (n >= NN) return;
    const int lane = threadIdx.x & 63;
    const int c2 = lane * 2;

    const float wl0 = W1last[c2], wl1 = W1last[c2 + 1];
    unsigned p2 = *(const unsigned*)(P + (size_t)n * 256 + 128 + c2);
    const float t20 = __uint_as_float(p2 << 16) + b1[c2];
    const float t21 = __uint_as_float(p2 & 0xffff0000u) + b1[c2 + 1];

    float a0 = 0.f, a1 = 0.f;
    const int beg = row_ptr[n], end = row_ptr[n + 1];
    int e = beg;
    for (; e + 1 < end; e += 2) {   // 2x unroll: two gathers in flight
        const int s0 = sSrc[e], s1 = sSrc[e + 1];
        const float w0 = sEw[e], w1 = sEw[e + 1];
        unsigned pa = *(const unsigned*)(P + (size_t)s0 * 256 + c2);
        unsigned pb = *(const unsigned*)(P + (size_t)s1 * 256 + c2);
        a0 += gelu_f(__uint_as_float(pa << 16) + t20 + w0 * wl0);
        a1 += gelu_f(__uint_as_float(pa & 0xffff0000u) + t21 + w0 * wl1);
        a0 += gelu_f(__uint_as_float(pb << 16) + t20 + w1 * wl0);
        a1 += gelu_f(__uint_as_float(pb & 0xffff0000u) + t21 + w1 * wl1);
    }
    if (e < end) {
        const int s0 = sSrc[e];
        const float w0 = sEw[e];
        unsigned pa = *(const unsigned*)(P + (size_t)s0 * 256 + c2);
        a0 += gelu_f(__uint_as_float(pa << 16) + t20 + w0 * wl0);
        a1 += gelu_f(__uint_as_float(pa & 0xffff0000u) + t21 + w0 * wl1);
    }
    float2 o; o.x = a0; o.y = a1;
    *(float2*)(S32 + (size_t)n * D + c2) = o;
}

// Node update on MFMA + residual + LayerNorm; optionally fused next-layer P-GEMM.
__global__ __launch_bounds__(256, 3) void node_mfma_kernel(
    const u16* __restrict__ hbf, const float* __restrict__ S32,
    const int* __restrict__ hist,
    const u16* __restrict__ NW1T, const float* __restrict__ ub1,
    const float* __restrict__ nb2p,
    const u16* __restrict__ W2T, const float* __restrict__ b2,
    const float* __restrict__ gamma, const float* __restrict__ beta,
    float* __restrict__ hidden_out, u16* __restrict__ hbf_out,
    const u16* __restrict__ PWTnext, u16* __restrict__ Pout, int write_f32)
{
    __shared__ u16 sA[64 * 264];
    __shared__ u16 sH1[64 * 136];
    __shared__ float s_cnt[64];
    float* sR = (float*)sA;
    const int tid = threadIdx.x;
    const int n0 = blockIdx.x * 64;

    if (tid < 64) {
        int n = n0 + tid; if (n >= NN) n = NN - 1;
        s_cnt[tid] = (float)hist[n];
    }
    {
        const int e = tid >> 2, q = tid & 3;
        int n = n0 + e; if (n >= NN) n = NN - 1;
        const uint4* hs = (const uint4*)(hbf + (size_t)n * D);
        const float4* ag = (const float4*)(S32 + (size_t)n * D);
        uint4* ar = (uint4*)(sA + e * 264);
#pragma unroll
        for (int c = 0; c < 8; ++c) {
            int cc = q * 8 + c;
            if (cc < 16) ar[cc] = hs[cc];
            else {
                float4 x0 = ag[(cc - 16) * 2];
                float4 x1 = ag[(cc - 16) * 2 + 1];
                uint4 p;
                p.x = (unsigned)f2bf(x0.x) | ((unsigned)f2bf(x0.y) << 16);
                p.y = (unsigned)f2bf(x0.z) | ((unsigned)f2bf(x0.w) << 16);
                p.z = (unsigned)f2bf(x1.x) | ((unsigned)f2bf(x1.y) << 16);
                p.w = (unsigned)f2bf(x1.z) | ((unsigned)f2bf(x1.w) << 16);
                ar[cc] = p;
            }
        }
    }
    __syncthreads();

    const int lane = tid & 63;
    const int l15 = lane & 15;
    const int quad = lane >> 4;
    const int nbase = (tid >> 6) * 32;

    f32x4 acc[4][2];
#pragma unroll
    for (int mt = 0; mt < 4; ++mt)
#pragma unroll
        for (int nt = 0; nt < 2; ++nt) acc[mt][nt] = (f32x4){0.f, 0.f, 0.f, 0.f};

    const u16* bp0 = NW1T + (size_t)(nbase + l15) * 256 + quad * 8;
    const u16* bp1 = bp0 + 16 * 256;
#pragma unroll
    for (int kb = 0; kb < 256; kb += 32) {
        bf16x8 bf0 = *(const bf16x8*)(bp0 + kb);
        bf16x8 bf1 = *(const bf16x8*)(bp1 + kb);
#pragma unroll
        for (int mt = 0; mt < 4; ++mt) {
            bf16x8 af = *(const bf16x8*)(sA + (mt * 16 + l15) * 264 + quad * 8 + kb);
            acc[mt][0] = __builtin_amdgcn_mfma_f32_16x16x32_bf16(af, bf0, acc[mt][0], 0, 0, 0);
            acc[mt][1] = __builtin_amdgcn_mfma_f32_16x16x32_bf16(af, bf1, acc[mt][1], 0, 0, 0);
        }
    }

    // epilogue 1: + ub1 + cnt*b2'; gelu -> sH1
#pragma unroll
    for (int mt = 0; mt < 4; ++mt)
#pragma unroll
        for (int nt = 0; nt < 2; ++nt) {
            const int col = nbase + nt * 16 + l15;
            const float bb = ub1[col];
            const float bp = nb2p[col];
#pragma unroll
            for (int r = 0; r < 4; ++r) {
                const int row = mt * 16 + quad * 4 + r;
                float v = acc[mt][nt][r] + bb + s_cnt[row] * bp;
                sH1[row * 136 + col] = f2bf(gelu_f(v));
            }
        }
    __syncthreads();

    f32x4 acc2[4][2];
#pragma unroll
    for (int mt = 0; mt < 4; ++mt)
#pragma unroll
        for (int nt = 0; nt < 2; ++nt) acc2[mt][nt] = (f32x4){0.f, 0.f, 0.f, 0.f};

    const u16* cp0 = W2T + (size_t)(nbase + l15) * 128 + quad * 8;
    const u16* cp1 = cp0 + 16 * 128;
#pragma unroll
    for (int kb = 0; kb < 128; kb += 32) {
        bf16x8 bf0 = *(const bf16x8*)(cp0 + kb);
        bf16x8 bf1 = *(const bf16x8*)(cp1 + kb);
#pragma unroll
        for (int mt = 0; mt < 4; ++mt) {
            bf16x8 af = *(const bf16x8*)(sH1 + (mt * 16 + l15) * 136 + quad * 8 + kb);
            acc2[mt][0] = __builtin_amdgcn_mfma_f32_16x16x32_bf16(af, bf0, acc2[mt][0], 0, 0, 0);
            acc2[mt][1] = __builtin_amdgcn_mfma_f32_16x16x32_bf16(af, bf1, acc2[mt][1], 0, 0, 0);
        }
    }

    // r = hbf + u -> sR (fp32)
#pragma unroll
    for (int mt = 0; mt < 4; ++mt)
#pragma unroll
        for (int nt = 0; nt < 2; ++nt) {
            const int col = nbase + nt * 16 + l15;
            const float bb = b2[col];
#pragma unroll
            for (int r = 0; r < 4; ++r) {
                const int row = mt * 16 + quad * 4 + r;
                int n = n0 + row; if (n >= NN) n = NN - 1;
                float h = __uint_as_float((unsigned)hbf[(size_t)n * D + col] << 16);
                sR[row * 132 + col] = acc2[mt][nt][r] + bb + h;
            }
        }
    __syncthreads();   // also: all sH1 reads (GEMM2) done before LN overwrites it

    // LayerNorm: 4 threads per node, 32 cols each; write hbf + stage new bf16 to sH1
    {
        const int e = tid >> 2, t4 = tid & 3;
        const int n = n0 + e;
        const float* rr = sR + e * 132 + t4 * 32;
        float s1 = 0.f, s2 = 0.f;
        float4 v[8];
#pragma unroll
        for (int i = 0; i < 8; ++i) {
            v[i] = *(const float4*)(rr + i * 4);
            s1 += v[i].x + v[i].y + v[i].z + v[i].w;
            s2 += v[i].x * v[i].x + v[i].y * v[i].y + v[i].z * v[i].z + v[i].w * v[i].w;
        }
        s1 += __shfl_xor(s1, 1); s2 += __shfl_xor(s2, 1);
        s1 += __shfl_xor(s1, 2); s2 += __shfl_xor(s2, 2);
        const float mean = s1 * (1.f / 128.f);
        const float var = s2 * (1.f / 128.f) - mean * mean;
        const float rs = rsqrtf(var + LN_EPS);
        float* op = hidden_out + (size_t)n * D + t4 * 32;
        u16* bp = hbf_out + (size_t)n * D + t4 * 32;
#pragma unroll
        for (int i = 0; i < 8; ++i) {
            const float4 g = *(const float4*)(gamma + t4 * 32 + i * 4);
            const float4 be = *(const float4*)(beta + t4 * 32 + i * 4);
            float4 o;
            o.x = (v[i].x - mean) * rs * g.x + be.x;
            o.y = (v[i].y - mean) * rs * g.y + be.y;
            o.z = (v[i].z - mean) * rs * g.z + be.z;
            o.w = (v[i].w - mean) * rs * g.w + be.w;
            uint2 pk;
            pk.x = (unsigned)f2bf(o.x) | ((unsigned)f2bf(o.y) << 16);
            pk.y = (unsigned)f2bf(o.z) | ((unsigned)f2bf(o.w) << 16);
            *(uint2*)(sH1 + e * 136 + t4 * 32 + i * 4) = pk;   // stage for fused P-GEMM
            if (n < NN) {
                if (write_f32) *(float4*)(op + i * 4) = o;
                *(uint2*)(bp + i * 4) = pk;
            }
        }
    }

    // fused next-layer projection: P = h_new @ PWTnext  (M=64, K=128, N=256)
    if (PWTnext) {
        __syncthreads();
        const int nbase4 = (tid >> 6) * 64;
        f32x4 accp[4][4];
#pragma unroll
        for (int mt = 0; mt < 4; ++mt)
#pragma unroll
            for (int nt = 0; nt < 4; ++nt) accp[mt][nt] = (f32x4){0.f, 0.f, 0.f, 0.f};

#pragma unroll
        for (int kb = 0; kb < 128; kb += 32) {
            bf16x8 bf[4];
#pragma unroll
            for (int nt = 0; nt < 4; ++nt)
                bf[nt] = *(const bf16x8*)(PWTnext + (size_t)(nbase4 + nt * 16 + l15) * 128 + quad * 8 + kb);
#pragma unroll
            for (int mt = 0; mt < 4; ++mt) {
                bf16x8 af = *(const bf16x8*)(sH1 + (mt * 16 + l15) * 136 + quad * 8 + kb);
#pragma unroll
                for (int nt = 0; nt < 4; ++nt)
                    accp[mt][nt] = __builtin_amdgcn_mfma_f32_16x16x32_bf16(af, bf[nt], accp[mt][nt], 0, 0, 0);
            }
        }
#pragma unroll
        for (int mt = 0; mt < 4; ++mt)
#pragma unroll
            for (int nt = 0; nt < 4; ++nt) {
                const int col = nbase4 + nt * 16 + l15;
#pragma unroll
                for (int r = 0; r < 4; ++r) {
                    const int row = mt * 16 + quad * 4 + r;
                    const int n = n0 + row;
                    if (n < NN) Pout[(size_t)n * 256 + col] = f2bf(accp[mt][nt][r]);
                }
            }
    }
}

// ---------------- pooling ----------------
__global__ __launch_bounds__(256) void count_kernel(
    const int* __restrict__ batch, float* __restrict__ counts)
{
    int t = blockIdx.x * 256 + threadIdx.x;
    const int chunk = (NN + 8191) / 8192;
    int beg = t * chunk, end = beg + chunk;
    if (end > NN) end = NN;
    if (beg >= NN) return;
    int cur = batch[beg];
    float cnt = 0.f;
    for (int i = beg; i < end; ++i) {
        int b = batch[i];
        if (b != cur) { atomicAdd(&counts[cur], cnt); cur = b; cnt = 0.f; }
        cnt += 1.f;
    }
    atomicAdd(&counts[cur], cnt);
}

__global__ __launch_bounds__(256) void pool_accum_kernel(
    const float* __restrict__ hidden, const int* __restrict__ batch,
    float* __restrict__ pooled)
{
    __shared__ int sb[128];
    const int n0 = blockIdx.x * 128;
    const int tid = threadIdx.x;
    if (tid < 128) sb[tid] = (n0 + tid < NN) ? batch[n0 + tid] : -1;
    __syncthreads();
    const int col = tid & 127, half = tid >> 7;
    const int base = half * 64;
    int cur = sb[base];
    float acc = 0.f;
    for (int i = 0; i < 64; ++i) {
        int n = n0 + base + i;
        if (n >= NN) break;
        int b = sb[base + i];
        if (b != cur) { atomicAdd(&pooled[cur * D + col], acc); cur = b; acc = 0.f; }
        acc += hidden[(size_t)n * D + col];
    }
    if (cur >= 0 && acc != 0.f) atomicAdd(&pooled[cur * D + col], acc);
}

__global__ __launch_bounds__(256) void pool_div_kernel(
    float* __restrict__ pooled, const float* __restrict__ counts)
{
    int i = blockIdx.x * 256 + threadIdx.x;
    pooled[i] /= fmaxf(counts[i >> 7], 1.0f);
}

extern "C" void kernel_launch(void* const* d_in, const int* in_sizes, int n_in,
                              void* d_out, int out_size, void* d_ws, size_t ws_size,
                              hipStream_t stream) {
    const float* X     = (const float*)d_in[0];
    const int*   eidx  = (const int*)d_in[1];
    const float* ew    = (const float*)d_in[2];
    const int*   batch = (const int*)d_in[3];
    const float* W_in  = (const float*)d_in[5];
    const float* b_in  = (const float*)d_in[6];
    const float* eW1   = (const float*)d_in[7];
    const float* eb1   = (const float*)d_in[8];
    const float* eW2   = (const float*)d_in[9];
    const float* eb2   = (const float*)d_in[10];
    const float* uW1   = (const float*)d_in[11];
    const float* ub1   = (const float*)d_in[12];
    const float* uW2   = (const float*)d_in[13];
    const float* ub2   = (const float*)d_in[14];
    const float* gamma = (const float*)d_in[15];
    const float* beta  = (const float*)d_in[16];

    float* out_hidden = (float*)d_out;
    float* out_pooled = out_hidden + (size_t)NN * D;

    u16*   hbf  = (u16*)d_ws;                                  // N*128 bf16
    u16*   P    = hbf + (size_t)NN * D;                        // N*256 bf16
    float* S32  = (float*)(P + (size_t)NN * 256);              // N*128 f32
    u16*   PWT  = (u16*)(S32 + (size_t)NN * D);                // NL*256*128
    u16*   NW1T = PWT + (size_t)NL * 256 * 128;                // NL*128*256
    u16*   uW2T = NW1T + (size_t)NL * 128 * 256;               // NL*128*128
    float* nb2p = (float*)(uW2T + (size_t)NL * 128 * 128);     // NL*128
    int*   hist    = (int*)(nb2p + (size_t)NL * 128);
    int*   row_ptr = hist + NN;                                // NN+1 ints
    int*   cursor  = row_ptr + NN + 1;
    int*   bsum    = cursor + NN;                              // SCAN_BLOCKS
    int*   boff    = bsum + SCAN_BLOCKS;                       // SCAN_BLOCKS
    int*   sSrc    = boff + SCAN_BLOCKS;
    float* sEw     = (float*)(sSrc + NE);
    float* counts  = sEw + NE;

    const int* src = eidx;
    const int* dst = eidx + NE;

    // CSR build (parallel 2-level scan)
    hipMemsetAsync(hist, 0, (size_t)NN * sizeof(int), stream);
    hist_kernel<<<NE / 256, 256, 0, stream>>>(dst, hist);
    bsum_kernel<<<SCAN_BLOCKS, 256, 0, stream>>>(hist, bsum);
    bscan_kernel<<<1, 256, 0, stream>>>(bsum, boff);
    emit_kernel<<<SCAN_BLOCKS, 256, 0, stream>>>(hist, boff, row_ptr, cursor);
    scatter_kernel<<<NE / 256, 256, 0, stream>>>(src, dst, ew, cursor, sSrc, sEw);

    // weight prep
    transpose_cvt2_kernel<<<192, 256, 0, stream>>>(eW1, PWT, 128, 128, 257 * 128, 256 * 128, 128);
    transpose_cvt2_kernel<<<192, 256, 0, stream>>>(eW1 + 128 * 128, PWT + 128 * 128, 128, 128, 257 * 128, 256 * 128, 128);
    transpose_cvt2_kernel<<<192, 256, 0, stream>>>(uW1, NW1T, 128, 128, 256 * 128, 128 * 256, 256);
    transpose_cvt2_kernel<<<192, 256, 0, stream>>>(uW2, uW2T, 128, 128, 128 * 128, 128 * 128, 128);
    w2p_kernel<<<192, 256, 0, stream>>>(eW2, uW1, NW1T);
    b2p_kernel<<<NL, 128, 0, stream>>>(eb2, uW1, nb2p);

    input_proj_kernel<<<(NN * D) / 256, 256, 0, stream>>>(X, W_in, b_in, hbf);

    const int nblk = (NN + 63) / 64;
    proj_kernel<<<nblk, 256, 0, stream>>>(hbf, PWT, P);   // layer-0 P
    for (int l = 0; l < NL; ++l) {
        edge_csr_kernel<<<(NN * 64 + 255) / 256, 256, 0, stream>>>(
            P, sSrc, sEw, row_ptr,
            eW1 + (size_t)l * 257 * 128 + 256 * 128,
            eb1 + (size_t)l * D, S32);
        const u16* pwt_next = (l < NL - 1) ? (PWT + (size_t)(l + 1) * 256 * 128) : nullptr;
        node_mfma_kernel<<<nblk, 256, 0, stream>>>(
            hbf, S32, hist,
            NW1T + (size_t)l * 128 * 256, ub1 + (size_t)l * D, nb2p + (size_t)l * D,
            uW2T + (size_t)l * 128 * 128, ub2 + (size_t)l * D,
            gamma + (size_t)l * D, beta + (size_t)l * D,
            out_hidden, hbf, pwt_next, P, (l == NL - 1) ? 1 : 0);
    }

    hipMemsetAsync(out_pooled, 0, (size_t)NG * D * sizeof(float), stream);
    hipMemsetAsync(counts, 0, (size_t)NG * sizeof(float), stream);
    count_kernel<<<32, 256, 0, stream>>>(batch, counts);
    pool_accum_kernel<<<(NN + 127) / 128, 256, 0, stream>>>(out_hidden, batch, out_pooled);
    pool_div_kernel<<<(NG * D) / 256, 256, 0, stream>>>(out_pooled, counts);
}

// Round 9
// 661.412 us; speedup vs baseline: 2.0535x; 1.0938x over previous
//
#include <hip/hip_runtime.h>
#include <math.h>

#define NN 50000
#define NE 800000
#define DIN 32
#define D 128
#define NL 3
#define NG 64
#define LN_EPS 1e-5f
#define SCAN_BLOCKS 196   // ceil(NN/256)

typedef unsigned short u16;
typedef __bf16 bf16x8 __attribute__((ext_vector_type(8)));
typedef float f32x4 __attribute__((ext_vector_type(4)));

__device__ __forceinline__ float gelu_f(float x) {
    return 0.5f * x * (1.0f + erff(x * 0.70710678118654752f));
}

__device__ __forceinline__ u16 f2bf(float x) {
    unsigned int u = __float_as_uint(x);
    u += 0x7fffu + ((u >> 16) & 1u);
    return (u16)(u >> 16);
}

// ---------------- CSR build: hist + 2-level scan + scatter ----------------
__global__ __launch_bounds__(256) void hist_kernel(
    const int* __restrict__ dst, int* __restrict__ hist)
{
    int e = blockIdx.x * 256 + threadIdx.x;
    atomicAdd(&hist[dst[e]], 1);
}

__global__ __launch_bounds__(256) void bsum_kernel(
    const int* __restrict__ hist, int* __restrict__ bsum)
{
    __shared__ int red[256];
    int i = blockIdx.x * 256 + threadIdx.x;
    red[threadIdx.x] = (i < NN) ? hist[i] : 0;
    __syncthreads();
    for (int off = 128; off > 0; off >>= 1) {
        if (threadIdx.x < off) red[threadIdx.x] += red[threadIdx.x + off];
        __syncthreads();
    }
    if (threadIdx.x == 0) bsum[blockIdx.x] = red[0];
}

__global__ __launch_bounds__(256) void bscan_kernel(
    const int* __restrict__ bsum, int* __restrict__ boff)
{
    __shared__ int sc[256];
    const int t = threadIdx.x;
    int orig = (t < SCAN_BLOCKS) ? bsum[t] : 0;
    sc[t] = orig;
    __syncthreads();
    for (int off = 1; off < 256; off <<= 1) {
        int v = (t >= off) ? sc[t - off] : 0;
        __syncthreads();
        sc[t] += v;
        __syncthreads();
    }
    if (t < SCAN_BLOCKS) boff[t] = sc[t] - orig;   // exclusive
}

__global__ __launch_bounds__(256) void emit_kernel(
    const int* __restrict__ hist, const int* __restrict__ boff,
    int* __restrict__ row_ptr, int* __restrict__ cursor)
{
    __shared__ int sc[256];
    const int t = threadIdx.x;
    const int i = blockIdx.x * 256 + t;
    int orig = (i < NN) ? hist[i] : 0;
    sc[t] = orig;
    __syncthreads();
    for (int off = 1; off < 256; off <<= 1) {
        int v = (t >= off) ? sc[t - off] : 0;
        __syncthreads();
        sc[t] += v;
        __syncthreads();
    }
    if (i < NN) {
        int ex = sc[t] - orig + boff[blockIdx.x];
        row_ptr[i] = ex;
        cursor[i] = ex;
    }
    if (i == 0) row_ptr[NN] = NE;
}

__global__ __launch_bounds__(256) void scatter_kernel(
    const int* __restrict__ src, const int* __restrict__ dst,
    const float* __restrict__ ew, int* __restrict__ cursor,
    int* __restrict__ sSrc, float* __restrict__ sEw)
{
    int e = blockIdx.x * 256 + threadIdx.x;
    int d = dst[e];
    int pos = atomicAdd(&cursor[d], 1);
    sSrc[pos] = src[e];
    sEw[pos] = ew[e];
}

// ---------------- projections / weight prep ----------------
__global__ __launch_bounds__(256) void input_proj_kernel(
    const float* __restrict__ X, const float* __restrict__ W,
    const float* __restrict__ b, u16* __restrict__ hbf)
{
    __shared__ float sW[DIN * D];
    for (int i = threadIdx.x; i < DIN * D; i += 256) sW[i] = W[i];
    __syncthreads();
    int o = blockIdx.x * 256 + threadIdx.x;
    int n = o >> 7, d = o & 127;
    const float* x = X + n * DIN;
    float acc = b[d];
#pragma unroll
    for (int k = 0; k < DIN; ++k) acc = fmaf(x[k], sW[k * D + d], acc);
    hbf[o] = f2bf(gelu_f(acc));
}

// dst[l*dstLS + n*dstRS + k] = bf16(src[l*srcLS + k*N + n])
__global__ __launch_bounds__(256) void transpose_cvt2_kernel(
    const float* __restrict__ src, u16* __restrict__ dst,
    int K, int N, int srcLS, int dstLS, int dstRS)
{
    int i = blockIdx.x * 256 + threadIdx.x;
    int per = K * N;
    int l = i / per;
    int r = i - l * per;
    int n = r / K;
    int k = r - n * K;
    dst[(size_t)l * dstLS + (size_t)n * dstRS + k] = f2bf(src[(size_t)l * srcLS + (size_t)k * N + n]);
}

// NW1T[l][n][128+k] = bf16( sum_j eW2[l][k][j] * uW1[l][128+j][n] )
__global__ __launch_bounds__(256) void w2p_kernel(
    const float* __restrict__ eW2, const float* __restrict__ uW1,
    u16* __restrict__ NW1T)
{
    int i = blockIdx.x * 256 + threadIdx.x;       // NL*128*128
    int l = i / 16384;
    int r = i - l * 16384;
    int n = r >> 7, k = r & 127;
    const float* w2row = eW2 + (size_t)l * 16384 + k * 128;
    const float* u1col = uW1 + (size_t)l * 32768 + 128 * 128 + n;
    float s = 0.f;
#pragma unroll 4
    for (int j = 0; j < 128; ++j) s = fmaf(w2row[j], u1col[j * 128], s);
    NW1T[(size_t)l * 32768 + n * 256 + 128 + k] = f2bf(s);
}

// nb2p[l][n] = sum_j eb2[l][j] * uW1[l][128+j][n]
__global__ __launch_bounds__(128) void b2p_kernel(
    const float* __restrict__ eb2, const float* __restrict__ uW1,
    float* __restrict__ nb2p)
{
    int l = blockIdx.x, n = threadIdx.x;
    const float* b2r = eb2 + l * 128;
    const float* u1col = uW1 + (size_t)l * 32768 + 128 * 128 + n;
    float s = 0.f;
#pragma unroll 4
    for (int j = 0; j < 128; ++j) s = fmaf(b2r[j], u1col[j * 128], s);
    nb2p[l * 128 + n] = s;
}

// P[n][0:256] = hbf[n] @ [W1a | W1b]  (layer-0 only) — LDS-coalesced stores
__global__ __launch_bounds__(256) void proj_kernel(
    const u16* __restrict__ hbf, const u16* __restrict__ PWT,
    u16* __restrict__ P)
{
    __shared__ u16 sA[64 * 136];
    __shared__ u16 sP[64 * 264];
    const int tid = threadIdx.x;
    const int n0 = blockIdx.x * 64;
    {
        const int e = tid >> 2, q = tid & 3;
        int n = n0 + e; if (n >= NN) n = NN - 1;
        const uint4* hs = (const uint4*)(hbf + (size_t)n * D);
        uint4* ar = (uint4*)(sA + e * 136);
#pragma unroll
        for (int c = 0; c < 4; ++c) ar[q * 4 + c] = hs[q * 4 + c];
    }
    __syncthreads();

    const int lane = tid & 63;
    const int l15 = lane & 15;
    const int quad = lane >> 4;
    const int nbase = (tid >> 6) * 64;

    f32x4 acc[4][4];
#pragma unroll
    for (int mt = 0; mt < 4; ++mt)
#pragma unroll
        for (int nt = 0; nt < 4; ++nt) acc[mt][nt] = (f32x4){0.f, 0.f, 0.f, 0.f};

#pragma unroll
    for (int kb = 0; kb < 128; kb += 32) {
        bf16x8 bf[4];
#pragma unroll
        for (int nt = 0; nt < 4; ++nt)
            bf[nt] = *(const bf16x8*)(PWT + (size_t)(nbase + nt * 16 + l15) * 128 + quad * 8 + kb);
#pragma unroll
        for (int mt = 0; mt < 4; ++mt) {
            bf16x8 af = *(const bf16x8*)(sA + (mt * 16 + l15) * 136 + quad * 8 + kb);
#pragma unroll
            for (int nt = 0; nt < 4; ++nt)
                acc[mt][nt] = __builtin_amdgcn_mfma_f32_16x16x32_bf16(af, bf[nt], acc[mt][nt], 0, 0, 0);
        }
    }

#pragma unroll
    for (int mt = 0; mt < 4; ++mt)
#pragma unroll
        for (int nt = 0; nt < 4; ++nt) {
            const int col = nbase + nt * 16 + l15;
#pragma unroll
            for (int r = 0; r < 4; ++r)
                sP[(mt * 16 + quad * 4 + r) * 264 + col] = f2bf(acc[mt][nt][r]);
        }
    __syncthreads();
    {   // cooperative coalesced store: 4 threads/row x 8 uint4, lane-contiguous
        const int e = tid >> 2, q = tid & 3;
        const int n = n0 + e;
        if (n < NN) {
            uint4* op = (uint4*)(P + (size_t)n * 256);
            const u16* sp = sP + e * 264;
#pragma unroll
            for (int c = 0; c < 8; ++c) op[q + c * 4] = *(const uint4*)(sp + (q + c * 4) * 8);
        }
    }
}

// CSR edge pass: one wave per dst node, lane owns 2 cols. Zero atomics.
// Writes S directly as packed bf16 (coalesced dword/lane).
__global__ __launch_bounds__(256) void edge_csr_kernel(
    const u16* __restrict__ P, const int* __restrict__ sSrc,
    const float* __restrict__ sEw, const int* __restrict__ row_ptr,
    const float* __restrict__ W1last, const float* __restrict__ b1,
    u16* __restrict__ Sbf)
{
    const int n = (blockIdx.x * 256 + threadIdx.x) >> 6;
    if (n >= NN) return;
    const int lane = threadIdx.x & 63;
    const int c2 = lane * 2;

    const float wl0 = W1last[c2], wl1 = W1last[c2 + 1];
    unsigned p2 = *(const unsigned*)(P + (size_t)n * 256 + 128 + c2);
    const float t20 = __uint_as_float(p2 << 16) + b1[c2];
    const float t21 = __uint_as_float(p2 & 0xffff0000u) + b1[c2 + 1];

    float a0 = 0.f, a1 = 0.f;
    const int beg = row_ptr[n], end = row_ptr[n + 1];
    int e = beg;
    for (; e + 1 < end; e += 2) {   // 2x unroll: two gathers in flight
        const int s0 = sSrc[e], s1 = sSrc[e + 1];
        const float w0 = sEw[e], w1 = sEw[e + 1];
        unsigned pa = *(const unsigned*)(P + (size_t)s0 * 256 + c2);
        unsigned pb = *(const unsigned*)(P + (size_t)s1 * 256 + c2);
        a0 += gelu_f(__uint_as_float(pa << 16) + t20 + w0 * wl0);
        a1 += gelu_f(__uint_as_float(pa & 0xffff0000u) + t21 + w0 * wl1);
        a0 += gelu_f(__uint_as_float(pb << 16) + t20 + w1 * wl0);
        a1 += gelu_f(__uint_as_float(pb & 0xffff0000u) + t21 + w1 * wl1);
    }
    if (e < end) {
        const int s0 = sSrc[e];
        const float w0 = sEw[e];
        unsigned pa = *(const unsigned*)(P + (size_t)s0 * 256 + c2);
        a0 += gelu_f(__uint_as_float(pa << 16) + t20 + w0 * wl0);
        a1 += gelu_f(__uint_as_float(pa & 0xffff0000u) + t21 + w0 * wl1);
    }
    unsigned pk = (unsigned)f2bf(a0) | ((unsigned)f2bf(a1) << 16);
    *(unsigned*)(Sbf + (size_t)n * D + c2) = pk;
}

// Node update on MFMA + residual + LayerNorm; optional fused next-layer P-GEMM.
// All global stores go through LDS and out as lane-contiguous uint4/float4.
__global__ __launch_bounds__(256, 3) void node_mfma_kernel(
    const u16* __restrict__ hbf, const u16* __restrict__ Sbf,
    const int* __restrict__ hist,
    const u16* __restrict__ NW1T, const float* __restrict__ ub1,
    const float* __restrict__ nb2p,
    const u16* __restrict__ W2T, const float* __restrict__ b2,
    const float* __restrict__ gamma, const float* __restrict__ beta,
    float* __restrict__ hidden_out, u16* __restrict__ hbf_out,
    const u16* __restrict__ PWTnext, u16* __restrict__ Pout, int write_f32)
{
    __shared__ u16 sA[64 * 264];
    __shared__ u16 sH1[64 * 136];
    __shared__ float s_cnt[64];
    float* sR = (float*)sA;        // fp32 residual view (also reused as sP u16)
    const int tid = threadIdx.x;
    const int n0 = blockIdx.x * 64;

    if (tid < 64) {
        int n = n0 + tid; if (n >= NN) n = NN - 1;
        s_cnt[tid] = (float)hist[n];
    }
    {   // stage A = [hbf | Sbf] (both bf16): 32 uint4 chunks/row, 8 per thread
        const int e = tid >> 2, q = tid & 3;
        int n = n0 + e; if (n >= NN) n = NN - 1;
        const uint4* hs = (const uint4*)(hbf + (size_t)n * D);
        const uint4* ss = (const uint4*)(Sbf + (size_t)n * D);
        uint4* ar = (uint4*)(sA + e * 264);
#pragma unroll
        for (int c = 0; c < 8; ++c) {
            int cc = q * 8 + c;
            ar[cc] = (cc < 16) ? hs[cc] : ss[cc - 16];
        }
    }
    __syncthreads();

    const int lane = tid & 63;
    const int l15 = lane & 15;
    const int quad = lane >> 4;
    const int nbase = (tid >> 6) * 32;

    f32x4 acc[4][2];
#pragma unroll
    for (int mt = 0; mt < 4; ++mt)
#pragma unroll
        for (int nt = 0; nt < 2; ++nt) acc[mt][nt] = (f32x4){0.f, 0.f, 0.f, 0.f};

    const u16* bp0 = NW1T + (size_t)(nbase + l15) * 256 + quad * 8;
    const u16* bp1 = bp0 + 16 * 256;
#pragma unroll
    for (int kb = 0; kb < 256; kb += 32) {
        bf16x8 bf0 = *(const bf16x8*)(bp0 + kb);
        bf16x8 bf1 = *(const bf16x8*)(bp1 + kb);
#pragma unroll
        for (int mt = 0; mt < 4; ++mt) {
            bf16x8 af = *(const bf16x8*)(sA + (mt * 16 + l15) * 264 + quad * 8 + kb);
            acc[mt][0] = __builtin_amdgcn_mfma_f32_16x16x32_bf16(af, bf0, acc[mt][0], 0, 0, 0);
            acc[mt][1] = __builtin_amdgcn_mfma_f32_16x16x32_bf16(af, bf1, acc[mt][1], 0, 0, 0);
        }
    }

    // epilogue 1: + ub1 + cnt*b2'; gelu -> sH1
#pragma unroll
    for (int mt = 0; mt < 4; ++mt)
#pragma unroll
        for (int nt = 0; nt < 2; ++nt) {
            const int col = nbase + nt * 16 + l15;
            const float bb = ub1[col];
            const float bp = nb2p[col];
#pragma unroll
            for (int r = 0; r < 4; ++r) {
                const int row = mt * 16 + quad * 4 + r;
                float v = acc[mt][nt][r] + bb + s_cnt[row] * bp;
                sH1[row * 136 + col] = f2bf(gelu_f(v));
            }
        }
    __syncthreads();

    f32x4 acc2[4][2];
#pragma unroll
    for (int mt = 0; mt < 4; ++mt)
#pragma unroll
        for (int nt = 0; nt < 2; ++nt) acc2[mt][nt] = (f32x4){0.f, 0.f, 0.f, 0.f};

    const u16* cp0 = W2T + (size_t)(nbase + l15) * 128 + quad * 8;
    const u16* cp1 = cp0 + 16 * 128;
#pragma unroll
    for (int kb = 0; kb < 128; kb += 32) {
        bf16x8 bf0 = *(const bf16x8*)(cp0 + kb);
        bf16x8 bf1 = *(const bf16x8*)(cp1 + kb);
#pragma unroll
        for (int mt = 0; mt < 4; ++mt) {
            bf16x8 af = *(const bf16x8*)(sH1 + (mt * 16 + l15) * 136 + quad * 8 + kb);
            acc2[mt][0] = __builtin_amdgcn_mfma_f32_16x16x32_bf16(af, bf0, acc2[mt][0], 0, 0, 0);
            acc2[mt][1] = __builtin_amdgcn_mfma_f32_16x16x32_bf16(af, bf1, acc2[mt][1], 0, 0, 0);
        }
    }

    // r = hbf + u -> sR (fp32)
#pragma unroll
    for (int mt = 0; mt < 4; ++mt)
#pragma unroll
        for (int nt = 0; nt < 2; ++nt) {
            const int col = nbase + nt * 16 + l15;
            const float bb = b2[col];
#pragma unroll
            for (int r = 0; r < 4; ++r) {
                const int row = mt * 16 + quad * 4 + r;
                int n = n0 + row; if (n >= NN) n = NN - 1;
                float h = __uint_as_float((unsigned)hbf[(size_t)n * D + col] << 16);
                sR[row * 132 + col] = acc2[mt][nt][r] + bb + h;
            }
        }
    __syncthreads();   // GEMM2's sH1 reads done; sR ready

    // LayerNorm: 4 threads/node, 32 cols each; bf16 -> sH1, f32 -> sR (if needed)
    {
        const int e = tid >> 2, t4 = tid & 3;
        float* rr = sR + e * 132 + t4 * 32;
        float s1 = 0.f, s2 = 0.f;
        float4 v[8];
#pragma unroll
        for (int i = 0; i < 8; ++i) {
            v[i] = *(const float4*)(rr + i * 4);
            s1 += v[i].x + v[i].y + v[i].z + v[i].w;
            s2 += v[i].x * v[i].x + v[i].y * v[i].y + v[i].z * v[i].z + v[i].w * v[i].w;
        }
        s1 += __shfl_xor(s1, 1); s2 += __shfl_xor(s2, 1);
        s1 += __shfl_xor(s1, 2); s2 += __shfl_xor(s2, 2);
        const float mean = s1 * (1.f / 128.f);
        const float var = s2 * (1.f / 128.f) - mean * mean;
        const float rs = rsqrtf(var + LN_EPS);
#pragma unroll
        for (int i = 0; i < 8; ++i) {
            const float4 g = *(const float4*)(gamma + t4 * 32 + i * 4);
            const float4 be = *(const float4*)(beta + t4 * 32 + i * 4);
            float4 o;
            o.x = (v[i].x - mean) * rs * g.x + be.x;
            o.y = (v[i].y - mean) * rs * g.y + be.y;
            o.z = (v[i].z - mean) * rs * g.z + be.z;
            o.w = (v[i].w - mean) * rs * g.w + be.w;
            uint2 pk;
            pk.x = (unsigned)f2bf(o.x) | ((unsigned)f2bf(o.y) << 16);
            pk.y = (unsigned)f2bf(o.z) | ((unsigned)f2bf(o.w) << 16);
            *(uint2*)(sH1 + e * 136 + t4 * 32 + i * 4) = pk;
            if (write_f32) *(float4*)(rr + i * 4) = o;   // stage normalized f32
        }
    }
    __syncthreads();

    // cooperative coalesced stores
    {
        const int e = tid >> 2, q = tid & 3;
        const int n = n0 + e;
        if (n < NN) {
            uint4* hp = (uint4*)(hbf_out + (size_t)n * D);       // 16 chunks/row
            const u16* sh = sH1 + e * 136;
#pragma unroll
            for (int c = 0; c < 4; ++c) hp[q + c * 4] = *(const uint4*)(sh + (q + c * 4) * 8);
            if (write_f32) {
                float4* op = (float4*)(hidden_out + (size_t)n * D);  // 32 chunks/row
                const float* sr = sR + e * 132;
#pragma unroll
                for (int c = 0; c < 8; ++c) op[q + c * 4] = *(const float4*)(sr + (q + c * 4) * 4);
            }
        }
    }

    // fused next-layer projection: P = h_new @ PWTnext  (M=64, K=128, N=256)
    if (PWTnext) {
        const int nbase4 = (tid >> 6) * 64;
        f32x4 accp[4][4];
#pragma unroll
        for (int mt = 0; mt < 4; ++mt)
#pragma unroll
            for (int nt = 0; nt < 4; ++nt) accp[mt][nt] = (f32x4){0.f, 0.f, 0.f, 0.f};

#pragma unroll
        for (int kb = 0; kb < 128; kb += 32) {
            bf16x8 bf[4];
#pragma unroll
            for (int nt = 0; nt < 4; ++nt)
                bf[nt] = *(const bf16x8*)(PWTnext + (size_t)(nbase4 + nt * 16 + l15) * 128 + quad * 8 + kb);
#pragma unroll
            for (int mt = 0; mt < 4; ++mt) {
                bf16x8 af = *(const bf16x8*)(sH1 + (mt * 16 + l15) * 136 + quad * 8 + kb);
#pragma unroll
                for (int nt = 0; nt < 4; ++nt)
                    accp[mt][nt] = __builtin_amdgcn_mfma_f32_16x16x32_bf16(af, bf[nt], accp[mt][nt], 0, 0, 0);
            }
        }
        __syncthreads();   // sR/sA reads done before sP overwrite
        u16* sP = sA;      // reuse as u16 64x264
#pragma unroll
        for (int mt = 0; mt < 4; ++mt)
#pragma unroll
            for (int nt = 0; nt < 4; ++nt) {
                const int col = nbase4 + nt * 16 + l15;
#pragma unroll
                for (int r = 0; r < 4; ++r)
                    sP[(mt * 16 + quad * 4 + r) * 264 + col] = f2bf(accp[mt][nt][r]);
            }
        __syncthreads();
        const int e = tid >> 2, q = tid & 3;
        const int n = n0 + e;
        if (n < NN) {
            uint4* op = (uint4*)(Pout + (size_t)n * 256);        // 32 chunks/row
            const u16* sp = sP + e * 264;
#pragma unroll
            for (int c = 0; c < 8; ++c) op[q + c * 4] = *(const uint4*)(sp + (q + c * 4) * 8);
        }
    }
}

// ---------------- pooling ----------------
__global__ __launch_bounds__(256) void count_kernel(
    const int* __restrict__ batch, float* __restrict__ counts)
{
    int t = blockIdx.x * 256 + threadIdx.x;
    const int chunk = (NN + 8191) / 8192;
    int beg = t * chunk, end = beg + chunk;
    if (end > NN) end = NN;
    if (beg >= NN) return;
    int cur = batch[beg];
    float cnt = 0.f;
    for (int i = beg; i < end; ++i) {
        int b = batch[i];
        if (b != cur) { atomicAdd(&counts[cur], cnt); cur = b; cnt = 0.f; }
        cnt += 1.f;
    }
    atomicAdd(&counts[cur], cnt);
}

__global__ __launch_bounds__(256) void pool_accum_kernel(
    const float* __restrict__ hidden, const int* __restrict__ batch,
    float* __restrict__ pooled)
{
    __shared__ int sb[128];
    const int n0 = blockIdx.x * 128;
    const int tid = threadIdx.x;
    if (tid < 128) sb[tid] = (n0 + tid < NN) ? batch[n0 + tid] : -1;
    __syncthreads();
    const int col = tid & 127, half = tid >> 7;
    const int base = half * 64;
    int cur = sb[base];
    float acc = 0.f;
    for (int i = 0; i < 64; ++i) {
        int n = n0 + base + i;
        if (n >= NN) break;
        int b = sb[base + i];
        if (b != cur) { atomicAdd(&pooled[cur * D + col], acc); cur = b; acc = 0.f; }
        acc += hidden[(size_t)n * D + col];
    }
    if (cur >= 0 && acc != 0.f) atomicAdd(&pooled[cur * D + col], acc);
}

__global__ __launch_bounds__(256) void pool_div_kernel(
    float* __restrict__ pooled, const float* __restrict__ counts)
{
    int i = blockIdx.x * 256 + threadIdx.x;
    pooled[i] /= fmaxf(counts[i >> 7], 1.0f);
}

extern "C" void kernel_launch(void* const* d_in, const int* in_sizes, int n_in,
                              void* d_out, int out_size, void* d_ws, size_t ws_size,
                              hipStream_t stream) {
    const float* X     = (const float*)d_in[0];
    const int*   eidx  = (const int*)d_in[1];
    const float* ew    = (const float*)d_in[2];
    const int*   batch = (const int*)d_in[3];
    const float* W_in  = (const float*)d_in[5];
    const float* b_in  = (const float*)d_in[6];
    const float* eW1   = (const float*)d_in[7];
    const float* eb1   = (const float*)d_in[8];
    const float* eW2   = (const float*)d_in[9];
    const float* eb2   = (const float*)d_in[10];
    const float* uW1   = (const float*)d_in[11];
    const float* ub1   = (const float*)d_in[12];
    const float* uW2   = (const float*)d_in[13];
    const float* ub2   = (const float*)d_in[14];
    const float* gamma = (const float*)d_in[15];
    const float* beta  = (const float*)d_in[16];

    float* out_hidden = (float*)d_out;
    float* out_pooled = out_hidden + (size_t)NN * D;

    u16*   hbf  = (u16*)d_ws;                                  // N*128 bf16
    u16*   P    = hbf + (size_t)NN * D;                        // N*256 bf16
    u16*   Sbf  = P + (size_t)NN * 256;                        // N*128 bf16
    u16*   PWT  = Sbf + (size_t)NN * D;                        // NL*256*128
    u16*   NW1T = PWT + (size_t)NL * 256 * 128;                // NL*128*256
    u16*   uW2T = NW1T + (size_t)NL * 128 * 256;               // NL*128*128
    float* nb2p = (float*)(uW2T + (size_t)NL * 128 * 128);     // NL*128
    int*   hist    = (int*)(nb2p + (size_t)NL * 128);
    int*   row_ptr = hist + NN;                                // NN+1 ints
    int*   cursor  = row_ptr + NN + 1;
    int*   bsum    = cursor + NN;                              // SCAN_BLOCKS
    int*   boff    = bsum + SCAN_BLOCKS;                       // SCAN_BLOCKS
    int*   sSrc    = boff + SCAN_BLOCKS;
    float* sEw     = (float*)(sSrc + NE);
    float* counts  = sEw + NE;

    const int* src = eidx;
    const int* dst = eidx + NE;

    // CSR build (parallel 2-level scan)
    hipMemsetAsync(hist, 0, (size_t)NN * sizeof(int), stream);
    hist_kernel<<<NE / 256, 256, 0, stream>>>(dst, hist);
    bsum_kernel<<<SCAN_BLOCKS, 256, 0, stream>>>(hist, bsum);
    bscan_kernel<<<1, 256, 0, stream>>>(bsum, boff);
    emit_kernel<<<SCAN_BLOCKS, 256, 0, stream>>>(hist, boff, row_ptr, cursor);
    scatter_kernel<<<NE / 256, 256, 0, stream>>>(src, dst, ew, cursor, sSrc, sEw);

    // weight prep
    transpose_cvt2_kernel<<<192, 256, 0, stream>>>(eW1, PWT, 128, 128, 257 * 128, 256 * 128, 128);
    transpose_cvt2_kernel<<<192, 256, 0, stream>>>(eW1 + 128 * 128, PWT + 128 * 128, 128, 128, 257 * 128, 256 * 128, 128);
    transpose_cvt2_kernel<<<192, 256, 0, stream>>>(uW1, NW1T, 128, 128, 256 * 128, 128 * 256, 256);
    transpose_cvt2_kernel<<<192, 256, 0, stream>>>(uW2, uW2T, 128, 128, 128 * 128, 128 * 128, 128);
    w2p_kernel<<<192, 256, 0, stream>>>(eW2, uW1, NW1T);
    b2p_kernel<<<NL, 128, 0, stream>>>(eb2, uW1, nb2p);

    input_proj_kernel<<<(NN * D) / 256, 256, 0, stream>>>(X, W_in, b_in, hbf);

    const int nblk = (NN + 63) / 64;
    proj_kernel<<<nblk, 256, 0, stream>>>(hbf, PWT, P);   // layer-0 P
    for (int l = 0; l < NL; ++l) {
        edge_csr_kernel<<<(NN * 64 + 255) / 256, 256, 0, stream>>>(
            P, sSrc, sEw, row_ptr,
            eW1 + (size_t)l * 257 * 128 + 256 * 128,
            eb1 + (size_t)l * D, Sbf);
        const u16* pwt_next = (l < NL - 1) ? (PWT + (size_t)(l + 1) * 256 * 128) : nullptr;
        node_mfma_kernel<<<nblk, 256, 0, stream>>>(
            hbf, Sbf, hist,
            NW1T + (size_t)l * 128 * 256, ub1 + (size_t)l * D, nb2p + (size_t)l * D,
            uW2T + (size_t)l * 128 * 128, ub2 + (size_t)l * D,
            gamma + (size_t)l * D, beta + (size_t)l * D,
            out_hidden, hbf, pwt_next, P, (l == NL - 1) ? 1 : 0);
    }

    hipMemsetAsync(out_pooled, 0, (size_t)NG * D * sizeof(float), stream);
    hipMemsetAsync(counts, 0, (size_t)NG * sizeof(float), stream);
    count_kernel<<<32, 256, 0, stream>>>(batch, counts);
    pool_accum_kernel<<<(NN + 127) / 128, 256, 0, stream>>>(out_hidden, batch, out_pooled);
    pool_div_kernel<<<(NG * D) / 256, 256, 0, stream>>>(out_pooled, counts);
}